// Round 2
// baseline (2249.028 us; speedup 1.0000x reference)
//
#include <hip/hip_runtime.h>
#include <hip/hip_bf16.h>
#include <math.h>

#define BB 4
#define CC 512
#define NHEAD 8
#define HDIM 64
#define NCLS 128
#define DD 768
#define LL 9216
#define BLPIX 36864
#define EPSV 1e-5f
#define GMBLK 144
#define AUXBLK 36
#define LSPLIT 8

typedef __hip_bfloat16 bf16;
__device__ __forceinline__ float bf2f(bf16 v){ return __bfloat162float(v); }
__device__ __forceinline__ bf16 f2bf(float v){ return __float2bfloat16(v); }

__global__ void ln_stats_k(const float* __restrict__ X, float* __restrict__ mu, float* __restrict__ rs){
  int idx = blockIdx.x * blockDim.x + threadIdx.x;
  if (idx >= BLPIX) return;
  int b = idx / LL, l = idx % LL;
  const float* p = X + (size_t)b * CC * LL + l;
  float s = 0.f, ss = 0.f;
  #pragma unroll 8
  for (int c = 0; c < CC; c++){ float v = p[(size_t)c * LL]; s += v; ss += v * v; }
  float m = s * (1.0f / CC);
  float var = ss * (1.0f / CC) - m * m;
  mu[idx] = m; rs[idx] = rsqrtf(var + EPSV);
}

template<int MODE>
__global__ __launch_bounds__(256) void gemm_k(
    const float* __restrict__ A,
    const float* __restrict__ resid,
    const bf16*  __restrict__ Bbf,
    const float* __restrict__ Bf,
    const float* __restrict__ mu, const float* __restrict__ rs,
    const float* __restrict__ lng, const float* __restrict__ lnb,
    const float* __restrict__ bias,
    bf16* __restrict__ q_out, bf16* __restrict__ k_out, bf16* __restrict__ v_out,
    float* __restrict__ xf_out,
    bf16* __restrict__ hb_out)
{
  __shared__ float As[16][68];
  __shared__ float Bs[16][68];
  int tid = threadIdx.x;
  int tx = tid & 15, ty = tid >> 4;
  int m0 = blockIdx.x * 64;
  int n0 = blockIdx.y * 64;
  float acc[4][4] = {};
  int ar = tid >> 2;
  int ak = (tid & 3) * 4;
  int bn = tid & 63;
  int bk0 = tid >> 6;
  int gb = (n0 + bn) / LL;
  int gl = (n0 + bn) % LL;
  int nidx = n0 + bn;
  for (int k0 = 0; k0 < 512; k0 += 16){
    float4 av = *reinterpret_cast<const float4*>(A + (size_t)(m0 + ar) * 512 + k0 + ak);
    As[ak + 0][ar] = av.x; As[ak + 1][ar] = av.y; As[ak + 2][ar] = av.z; As[ak + 3][ar] = av.w;
    #pragma unroll
    for (int i = 0; i < 4; i++){
      int kk = bk0 + i * 4;
      int c = k0 + kk;
      float v;
      if (MODE == 0){
        float xv = resid[(size_t)gb * CC * LL + (size_t)c * LL + gl];
        v = (xv - mu[nidx]) * rs[nidx] * lng[c] + lnb[c];
      } else if (MODE == 1){
        v = bf2f(Bbf[(size_t)gb * CC * LL + (size_t)c * LL + gl]);
      } else if (MODE == 2){
        float xv = Bf[(size_t)gb * CC * LL + (size_t)c * LL + gl];
        v = (xv - mu[nidx]) * rs[nidx] * lng[c] + lnb[c];
      } else {
        v = bf2f(Bbf[(size_t)gb * CC * LL + (size_t)c * LL + gl]);
      }
      Bs[kk][bn] = v;
    }
    __syncthreads();
    #pragma unroll
    for (int kk = 0; kk < 16; kk++){
      float ra[4], rb[4];
      #pragma unroll
      for (int i = 0; i < 4; i++) ra[i] = As[kk][ty * 4 + i];
      #pragma unroll
      for (int j = 0; j < 4; j++) rb[j] = Bs[kk][tx + 16 * j];
      #pragma unroll
      for (int i = 0; i < 4; i++)
        #pragma unroll
        for (int j = 0; j < 4; j++) acc[i][j] += ra[i] * rb[j];
    }
    __syncthreads();
  }
  #pragma unroll
  for (int i = 0; i < 4; i++){
    int m = m0 + ty * 4 + i;
    #pragma unroll
    for (int j = 0; j < 4; j++){
      int n = n0 + tx + 16 * j;
      int b = n / LL, l = n % LL;
      float v = acc[i][j];
      if (MODE == 0){
        int part = m >> 9;
        int ch = m & 511;
        size_t o = (size_t)b * CC * LL + (size_t)ch * LL + l;
        bf16 bv = f2bf(v);
        if (part == 0) q_out[o] = bv; else if (part == 1) k_out[o] = bv; else v_out[o] = bv;
      } else if (MODE == 1){
        size_t o = (size_t)b * CC * LL + (size_t)m * LL + l;
        xf_out[o] = resid[o] + v + bias[m];
      } else if (MODE == 2){
        float t = v + bias[m];
        float gv = 0.5f * t * (1.0f + erff(t * 0.70710678118654752f));
        size_t o = (size_t)b * CC * LL + (size_t)m * LL + l;
        hb_out[o] = f2bf(gv);
      } else {
        size_t o = (size_t)b * CC * LL + (size_t)m * LL + l;
        xf_out[o] = resid[o] + v + bias[m];
      }
    }
  }
}

__global__ void rownorm_k(const bf16* __restrict__ q, const bf16* __restrict__ k,
                          float* __restrict__ qn, float* __restrict__ kn){
  __shared__ float red[256];
  int row = blockIdx.x;
  const bf16* src = (row < 2048) ? q : k;
  int r = (row < 2048) ? row : row - 2048;
  const bf16* p = src + (size_t)r * LL;
  float s = 0.f;
  for (int i = threadIdx.x; i < LL; i += 256){ float v = bf2f(p[i]); s += v * v; }
  red[threadIdx.x] = s; __syncthreads();
  for (int st = 128; st > 0; st >>= 1){ if (threadIdx.x < st) red[threadIdx.x] += red[threadIdx.x + st]; __syncthreads(); }
  if (threadIdx.x == 0){
    float nv = fmaxf(sqrtf(red[0]), 1e-12f);
    if (row < 2048) qn[r] = nv; else kn[r] = nv;
  }
}

__global__ void clsg_k(const float* __restrict__ cls_embs, const float* __restrict__ gamma_g,
                       const float* __restrict__ beta_g, const float* __restrict__ Wg,
                       float* __restrict__ g, float* __restrict__ gn){
  __shared__ float cn[DD];
  __shared__ float red[256];
  __shared__ float gsh[CC];
  __shared__ float nrm[NHEAD];
  int n = blockIdx.x;
  const float* e = cls_embs + (size_t)n * DD;
  float s = 0.f, ss = 0.f;
  for (int i = threadIdx.x; i < DD; i += 256){ float v = e[i]; s += v; ss += v * v; }
  red[threadIdx.x] = s; __syncthreads();
  for (int st = 128; st > 0; st >>= 1){ if (threadIdx.x < st) red[threadIdx.x] += red[threadIdx.x + st]; __syncthreads(); }
  float mean = red[0] / DD; __syncthreads();
  red[threadIdx.x] = ss; __syncthreads();
  for (int st = 128; st > 0; st >>= 1){ if (threadIdx.x < st) red[threadIdx.x] += red[threadIdx.x + st]; __syncthreads(); }
  float var = red[0] / DD - mean * mean;
  float rstd = rsqrtf(var + EPSV);
  __syncthreads();
  for (int i = threadIdx.x; i < DD; i += 256) cn[i] = (e[i] - mean) * rstd * gamma_g[i] + beta_g[i];
  __syncthreads();
  for (int c = threadIdx.x; c < CC; c += 256){
    const float* w = Wg + (size_t)c * DD;
    float a = 0.f;
    #pragma unroll 8
    for (int d = 0; d < DD; d++) a += cn[d] * w[d];
    gsh[c] = a;
  }
  __syncthreads();
  if (threadIdx.x < NHEAD){
    float a = 0.f;
    for (int d = 0; d < HDIM; d++){ float v = gsh[threadIdx.x * HDIM + d]; a += v * v; }
    nrm[threadIdx.x] = fmaxf(sqrtf(a), 1e-12f);
  }
  __syncthreads();
  for (int c = threadIdx.x; c < CC; c += 256){
    g[(size_t)n * CC + c] = gsh[c];
    gn[(size_t)n * CC + c] = gsh[c] / nrm[c >> 6];
  }
}

__global__ void clsobj_k(const float* __restrict__ g, const float* __restrict__ cls_l,
                         float* __restrict__ cls_obj){
  int idx = blockIdx.x * 256 + threadIdx.x;
  if (idx >= BB * CC) return;
  int b = idx >> 9, c = idx & 511;
  float a = 0.f;
  for (int n = 0; n < NCLS; n++) a += g[(size_t)n * CC + c] * cls_l[b * NCLS + n];
  cls_obj[idx] = a;
}

__global__ __launch_bounds__(256) void gm1_k(const bf16* __restrict__ q, const float* __restrict__ gn,
        float* __restrict__ pmin, float* __restrict__ pmax){
  __shared__ float smem[12800];
  float* qs = smem;
  float* gns = smem + 4352;
  float* rnorm = smem + 4352 + 8320;
  float* rmin = smem;
  float* rmax = smem + 2048;
  int bh = blockIdx.x;
  int lt = blockIdx.y;
  int l0 = lt * 64;
  int tid = threadIdx.x;
  int b = bh >> 3, h = bh & 7;
  const bf16* qp = q + (size_t)b * CC * LL + (size_t)h * HDIM * LL + l0;
  #pragma unroll
  for (int i = 0; i < 16; i++){
    int idx = tid + i * 256;
    int d = idx >> 6, ll = idx & 63;
    qs[d * 68 + ll] = bf2f(qp[(size_t)d * LL + ll]);
  }
  #pragma unroll
  for (int i = 0; i < 32; i++){
    int idx = tid + i * 256;
    int n = idx >> 6, d = idx & 63;
    gns[n * 65 + d] = gn[(size_t)n * CC + h * HDIM + d];
  }
  __syncthreads();
  if (tid < 64){
    float s = 0.f;
    for (int d = 0; d < 64; d++){ float v = qs[d * 68 + tid]; s += v * v; }
    rnorm[tid] = 1.0f / fmaxf(sqrtf(s), 1e-12f);
  }
  __syncthreads();
  int tx = tid & 15, ty = tid >> 4;
  float acc[8][4] = {};
  for (int d = 0; d < 64; d++){
    float qv[4], gv[8];
    #pragma unroll
    for (int j = 0; j < 4; j++) qv[j] = qs[d * 68 + tx * 4 + j];
    #pragma unroll
    for (int i = 0; i < 8; i++) gv[i] = gns[(ty * 8 + i) * 65 + d];
    #pragma unroll
    for (int i = 0; i < 8; i++)
      #pragma unroll
      for (int j = 0; j < 4; j++) acc[i][j] += gv[i] * qv[j];
  }
  __syncthreads();
  float tmn[8], tmx[8];
  #pragma unroll
  for (int i = 0; i < 8; i++){
    float mn = 1e30f, mx = -1e30f;
    #pragma unroll
    for (int j = 0; j < 4; j++){
      int l = tx * 4 + j;
      float v = acc[i][j] * rnorm[l];
      mn = fminf(mn, v); mx = fmaxf(mx, v);
    }
    tmn[i] = mn; tmx[i] = mx;
  }
  #pragma unroll
  for (int i = 0; i < 8; i++){
    int n = ty * 8 + i;
    rmin[n * 16 + tx] = tmn[i];
    rmax[n * 16 + tx] = tmx[i];
  }
  __syncthreads();
  if (tid < 128){
    float mn = 1e30f, mx = -1e30f;
    #pragma unroll
    for (int t = 0; t < 16; t++){ mn = fminf(mn, rmin[tid * 16 + t]); mx = fmaxf(mx, rmax[tid * 16 + t]); }
    pmin[((size_t)bh * 128 + tid) * GMBLK + lt] = mn;
    pmax[((size_t)bh * 128 + tid) * GMBLK + lt] = mx;
  }
}

__global__ void gmred_k(const float* __restrict__ pmin, const float* __restrict__ pmax,
                        float* __restrict__ gmin, float* __restrict__ gms){
  __shared__ float rmn[64], rmx[64];
  int row = blockIdx.x;
  float mn = 1e30f, mx = -1e30f;
  for (int i = threadIdx.x; i < GMBLK; i += 64){
    mn = fminf(mn, pmin[(size_t)row * GMBLK + i]);
    mx = fmaxf(mx, pmax[(size_t)row * GMBLK + i]);
  }
  rmn[threadIdx.x] = mn; rmx[threadIdx.x] = mx; __syncthreads();
  for (int st = 32; st > 0; st >>= 1){
    if (threadIdx.x < st){
      rmn[threadIdx.x] = fminf(rmn[threadIdx.x], rmn[threadIdx.x + st]);
      rmx[threadIdx.x] = fmaxf(rmx[threadIdx.x], rmx[threadIdx.x + st]);
    }
    __syncthreads();
  }
  if (threadIdx.x == 0){ gmin[row] = rmn[0]; gms[row] = rmx[0] - rmn[0]; }
}

__global__ void seg_k(const float* __restrict__ seg, const bf16* __restrict__ k, float* __restrict__ seg_num){
  __shared__ float red[256];
  int bc = blockIdx.x;
  int b = bc >> 9;
  const bf16* p = k + (size_t)bc * LL;
  const float* sp = seg + (size_t)b * LL;
  float s = 0.f;
  for (int i = threadIdx.x; i < LL; i += 256){
    float m = 1.0f / (1.0f + expf(-sp[i]));
    s += m * bf2f(p[i]);
  }
  red[threadIdx.x] = s; __syncthreads();
  for (int st = 128; st > 0; st >>= 1){ if (threadIdx.x < st) red[threadIdx.x] += red[threadIdx.x + st]; __syncthreads(); }
  if (threadIdx.x == 0) seg_num[bc] = red[0];
}

__global__ void segden_k(const float* __restrict__ seg, float* __restrict__ den){
  __shared__ float red[256];
  int b = blockIdx.x;
  const float* sp = seg + (size_t)b * LL;
  float s = 0.f;
  for (int i = threadIdx.x; i < LL; i += 256) s += 1.0f / (1.0f + expf(-sp[i]));
  red[threadIdx.x] = s; __syncthreads();
  for (int st = 128; st > 0; st >>= 1){ if (threadIdx.x < st) red[threadIdx.x] += red[threadIdx.x + st]; __syncthreads(); }
  if (threadIdx.x == 0) den[b] = red[0];
}

__global__ void obj_k(const float* __restrict__ cls_obj, const float* __restrict__ seg_num,
                      const float* __restrict__ den, float* __restrict__ obj){
  __shared__ float sval[2048];
  __shared__ float nrm[32];
  int tid = threadIdx.x;
  #pragma unroll
  for (int i = 0; i < 8; i++){
    int idx = tid + i * 256;
    int b = idx >> 9;
    sval[idx] = cls_obj[idx] + seg_num[idx] / den[b];
  }
  __syncthreads();
  if (tid < 32){
    float s = 0.f;
    for (int d = 0; d < 64; d++){ float v = sval[tid * 64 + d]; s += v * v; }
    nrm[tid] = fmaxf(sqrtf(s), 1e-12f);
  }
  __syncthreads();
  #pragma unroll
  for (int i = 0; i < 8; i++){
    int idx = tid + i * 256;
    obj[idx] = sval[idx] / nrm[idx >> 6];
  }
}

__global__ void aux_k(const bf16* __restrict__ k, const float* __restrict__ obj, float* __restrict__ aux,
                      float* __restrict__ pmin, float* __restrict__ pmax){
  __shared__ float os[64];
  __shared__ float rmn[256], rmx[256];
  int bh = blockIdx.x, lt = blockIdx.y;
  int b = bh >> 3, h = bh & 7;
  int l = lt * 256 + threadIdx.x;
  if (threadIdx.x < 64) os[threadIdx.x] = obj[bh * 64 + threadIdx.x];
  __syncthreads();
  const bf16* kp = k + (size_t)b * CC * LL + (size_t)h * HDIM * LL + l;
  float ss = 0.f, dot = 0.f;
  #pragma unroll 8
  for (int d = 0; d < 64; d++){ float v = bf2f(kp[(size_t)d * LL]); ss += v * v; dot += os[d] * v; }
  float av = dot / fmaxf(sqrtf(ss), 1e-12f);
  aux[(size_t)bh * LL + l] = av;
  rmn[threadIdx.x] = av; rmx[threadIdx.x] = av; __syncthreads();
  for (int st = 128; st > 0; st >>= 1){
    if (threadIdx.x < st){
      rmn[threadIdx.x] = fminf(rmn[threadIdx.x], rmn[threadIdx.x + st]);
      rmx[threadIdx.x] = fmaxf(rmx[threadIdx.x], rmx[threadIdx.x + st]);
    }
    __syncthreads();
  }
  if (threadIdx.x == 0){ pmin[bh * AUXBLK + lt] = rmn[0]; pmax[bh * AUXBLK + lt] = rmx[0]; }
}

__global__ void auxred_k(const float* __restrict__ pmin, const float* __restrict__ pmax,
                         float* __restrict__ amin, float* __restrict__ ams){
  __shared__ float rmn[64], rmx[64];
  int bh = blockIdx.x;
  float mn = 1e30f, mx = -1e30f;
  for (int i = threadIdx.x; i < AUXBLK; i += 64){
    mn = fminf(mn, pmin[bh * AUXBLK + i]);
    mx = fmaxf(mx, pmax[bh * AUXBLK + i]);
  }
  rmn[threadIdx.x] = mn; rmx[threadIdx.x] = mx; __syncthreads();
  for (int st = 32; st > 0; st >>= 1){
    if (threadIdx.x < st){
      rmn[threadIdx.x] = fminf(rmn[threadIdx.x], rmn[threadIdx.x + st]);
      rmx[threadIdx.x] = fmaxf(rmx[threadIdx.x], rmx[threadIdx.x + st]);
    }
    __syncthreads();
  }
  if (threadIdx.x == 0){ amin[bh] = rmn[0]; ams[bh] = rmx[0] - rmn[0]; }
}

__global__ __launch_bounds__(256) void attn_k(const bf16* __restrict__ q, const bf16* __restrict__ k,
                                              float* __restrict__ part){
  __shared__ float qs[64 * 68];
  __shared__ float ks[64 * 68];
  int ls = blockIdx.x, bh = blockIdx.y;
  int b = bh >> 3, h = bh & 7;
  int tid = threadIdx.x, tx = tid & 15, ty = tid >> 4;
  const bf16* qp = q + (size_t)b * CC * LL + (size_t)h * HDIM * LL;
  const bf16* kp = k + (size_t)b * CC * LL + (size_t)h * HDIM * LL;
  float acc[4][4] = {};
  for (int lt = ls * 18; lt < (ls + 1) * 18; lt++){
    int l0 = lt * 64;
    #pragma unroll
    for (int i = 0; i < 16; i++){
      int idx = tid + i * 256;
      int d = idx >> 6, ll = idx & 63;
      qs[d * 68 + ll] = bf2f(qp[(size_t)d * LL + l0 + ll]);
      ks[d * 68 + ll] = bf2f(kp[(size_t)d * LL + l0 + ll]);
    }
    __syncthreads();
    for (int ll = 0; ll < 64; ll++){
      float qv[4], kv[4];
      #pragma unroll
      for (int i = 0; i < 4; i++) qv[i] = qs[(ty * 4 + i) * 68 + ll];
      #pragma unroll
      for (int j = 0; j < 4; j++) kv[j] = ks[(tx * 4 + j) * 68 + ll];
      #pragma unroll
      for (int i = 0; i < 4; i++)
        #pragma unroll
        for (int j = 0; j < 4; j++) acc[i][j] += qv[i] * kv[j];
    }
    __syncthreads();
  }
  #pragma unroll
  for (int i = 0; i < 4; i++)
    #pragma unroll
    for (int j = 0; j < 4; j++){
      int d = ty * 4 + i, e = tx + 16 * j;
      part[((size_t)(bh * LSPLIT + ls)) * 4096 + d * 64 + e] = acc[i][j];
    }
}

__global__ void smax_k(const float* __restrict__ part, const float* __restrict__ qn,
                       const float* __restrict__ kn, const float* __restrict__ scale,
                       float* __restrict__ P){
  __shared__ float As[64 * 65];
  int bh = blockIdx.x;
  int h = bh & 7;
  int tid = threadIdx.x;
  #pragma unroll
  for (int i = 0; i < 16; i++){
    int cell = tid + i * 256;
    int d = cell >> 6, e = cell & 63;
    float s = 0.f;
    #pragma unroll
    for (int ls = 0; ls < LSPLIT; ls++) s += part[((size_t)(bh * LSPLIT + ls)) * 4096 + cell];
    As[d * 65 + e] = s * scale[h] / (qn[bh * 64 + d] * kn[bh * 64 + e]);
  }
  __syncthreads();
  if (tid < 64){
    int d = tid;
    float mx = -1e30f;
    for (int e = 0; e < 64; e++) mx = fmaxf(mx, As[d * 65 + e]);
    float sum = 0.f;
    for (int e = 0; e < 64; e++){ float ev = expf(As[d * 65 + e] - mx); As[d * 65 + e] = ev; sum += ev; }
    float inv = 1.0f / sum;
    for (int e = 0; e < 64; e++) P[(size_t)bh * 4096 + d * 64 + e] = As[d * 65 + e] * inv;
  }
}

__global__ __launch_bounds__(256) void pv_k(const bf16* __restrict__ q, const float* __restrict__ gn_all,
      const float* __restrict__ aux,
      const float* __restrict__ gmin, const float* __restrict__ gms,
      const float* __restrict__ amin, const float* __restrict__ ams,
      const float* __restrict__ P, const bf16* __restrict__ v, bf16* __restrict__ outb){
  __shared__ float Ps[4096];
  __shared__ float gns[8192];
  __shared__ float gmins[128], gmss[128];
  int bh = blockIdx.x, lt = blockIdx.y;
  int b = bh >> 3, h = bh & 7;
  int tid = threadIdx.x;
  int l = lt * 256 + tid;
  #pragma unroll
  for (int i = 0; i < 16; i++) Ps[tid + i * 256] = P[(size_t)bh * 4096 + tid + i * 256];
  #pragma unroll
  for (int i = 0; i < 32; i++){
    int idx = tid + i * 256;
    gns[idx] = gn_all[(size_t)(idx >> 6) * CC + h * HDIM + (idx & 63)];
  }
  if (tid < 128){ gmins[tid] = gmin[bh * 128 + tid]; gmss[tid] = gms[bh * 128 + tid]; }
  __syncthreads();
  const bf16* qp = q + (size_t)b * CC * LL + (size_t)h * HDIM * LL + l;
  float val[64];
  float ss = 0.f;
  #pragma unroll
  for (int d = 0; d < 64; d++){ float qv = bf2f(qp[(size_t)d * LL]); val[d] = qv; ss += qv * qv; }
  float rq = 1.0f / fmaxf(sqrtf(ss), 1e-12f);
  #pragma unroll
  for (int d = 0; d < 64; d++) val[d] *= rq;
  float se = 0.f, set = 0.f;
  for (int n = 0; n < 128; n++){
    float dot = 0.f;
    #pragma unroll
    for (int d = 0; d < 64; d++) dot += gns[n * 64 + d] * val[d];
    float t = (dot - gmins[n]) / gmss[n];
    float e = expf(t);
    se += e; set += e * t;
  }
  float gmred = set / se;
  float auxn = (aux[(size_t)bh * LL + l] - amin[bh]) / ams[bh];
  float gmf = gmred * auxn;
  const bf16* vp = v + (size_t)b * CC * LL + (size_t)h * HDIM * LL + l;
  #pragma unroll
  for (int e2 = 0; e2 < 64; e2++) val[e2] = gmf * bf2f(vp[(size_t)e2 * LL]);
  bf16* op = outb + (size_t)b * CC * LL + (size_t)h * HDIM * LL + l;
  for (int d = 0; d < 64; d++){
    float a = 0.f;
    #pragma unroll
    for (int e2 = 0; e2 < 64; e2++) a += Ps[d * 64 + e2] * val[e2];
    op[(size_t)d * LL] = f2bf(a);
  }
}

extern "C" void kernel_launch(void* const* d_in, const int* in_sizes, int n_in,
                              void* d_out, int out_size, void* d_ws, size_t ws_size,
                              hipStream_t stream){
  const float* img        = (const float*)d_in[0];
  const float* cls_embs   = (const float*)d_in[1];
  const float* cls_logits = (const float*)d_in[2];
  const float* seg        = (const float*)d_in[3];
  const float* gamma_g    = (const float*)d_in[4];
  const float* beta_g     = (const float*)d_in[5];
  const float* gamma_f    = (const float*)d_in[6];
  const float* beta_f     = (const float*)d_in[7];
  const float* attn_scale = (const float*)d_in[8];
  const float* Wg         = (const float*)d_in[9];
  const float* Wqkv       = (const float*)d_in[10];
  const float* Wo         = (const float*)d_in[11];
  const float* bo         = (const float*)d_in[12];
  const float* gamma_n    = (const float*)d_in[13];
  const float* beta_n     = (const float*)d_in[14];
  const float* W1         = (const float*)d_in[15];
  const float* b1         = (const float*)d_in[16];
  const float* W2         = (const float*)d_in[17];
  const float* b2         = (const float*)d_in[18];
  float* outp = (float*)d_out;
  (void)in_sizes; (void)n_in; (void)out_size;

  char* wsb = (char*)d_ws;
  size_t off = 0;
  auto alloc = [&](size_t bytes)->char*{
    char* p = wsb + off;
    off += (bytes + 255) & ~(size_t)255;
    return p;
  };
  float* mu1   = (float*)alloc((size_t)BLPIX * 4);
  float* rs1   = (float*)alloc((size_t)BLPIX * 4);
  float* qn    = (float*)alloc(2048 * 4);
  float* kn    = (float*)alloc(2048 * 4);
  float* gbuf  = (float*)alloc((size_t)NCLS * CC * 4);
  float* gnbuf = (float*)alloc((size_t)NCLS * CC * 4);
  float* clsov = (float*)alloc(2048 * 4);
  float* segn  = (float*)alloc(2048 * 4);
  float* segd  = (float*)alloc(256);
  float* objv  = (float*)alloc(2048 * 4);
  float* gminp = (float*)alloc((size_t)32 * 128 * GMBLK * 4);
  float* gmaxp = (float*)alloc((size_t)32 * 128 * GMBLK * 4);
  float* gminv = (float*)alloc(4096 * 4);
  float* gmsv  = (float*)alloc(4096 * 4);
  float* auxv  = (float*)alloc((size_t)32 * LL * 4);
  float* apmin = (float*)alloc(32 * AUXBLK * 4);
  float* apmax = (float*)alloc(32 * AUXBLK * 4);
  float* aminv = (float*)alloc(256);
  float* amsv  = (float*)alloc(256);
  float* Pbuf  = (float*)alloc((size_t)32 * 4096 * 4);
  float* apart = (float*)alloc((size_t)32 * LSPLIT * 4096 * 4);
  bf16* qb   = (bf16*)alloc((size_t)BB * CC * LL * 2);
  bf16* kb   = (bf16*)alloc((size_t)BB * CC * LL * 2);
  // Aliased buffers (lifetimes disjoint):
  bf16*  vb    = (bf16*)d_out;     // v lives in d_out until pv_k; Wo-GEMM then overwrites d_out with x
  bf16*  outbb = kb;               // attention output reuses k region (k dead after attn_k)
  bf16*  hb    = qb;               // MLP hidden reuses q region (q dead after pv_k)
  float* xb    = outp;             // x lives in d_out from Wo-GEMM onward
  if (off > ws_size) return;

  ln_stats_k<<<BLPIX / 256, 256, 0, stream>>>(img, mu1, rs1);
  gemm_k<0><<<dim3(24, 576), 256, 0, stream>>>(Wqkv, img, nullptr, nullptr, mu1, rs1,
      gamma_f, beta_f, nullptr, qb, kb, vb, nullptr, nullptr);
  rownorm_k<<<4096, 256, 0, stream>>>(qb, kb, qn, kn);
  clsg_k<<<NCLS, 256, 0, stream>>>(cls_embs, gamma_g, beta_g, Wg, gbuf, gnbuf);
  clsobj_k<<<8, 256, 0, stream>>>(gbuf, cls_logits, clsov);
  gm1_k<<<dim3(32, GMBLK), 256, 0, stream>>>(qb, gnbuf, gminp, gmaxp);
  gmred_k<<<4096, 64, 0, stream>>>(gminp, gmaxp, gminv, gmsv);
  seg_k<<<2048, 256, 0, stream>>>(seg, kb, segn);
  segden_k<<<BB, 256, 0, stream>>>(seg, segd);
  obj_k<<<1, 256, 0, stream>>>(clsov, segn, segd, objv);
  aux_k<<<dim3(32, AUXBLK), 256, 0, stream>>>(kb, objv, auxv, apmin, apmax);
  auxred_k<<<32, 64, 0, stream>>>(apmin, apmax, aminv, amsv);
  attn_k<<<dim3(LSPLIT, 32), 256, 0, stream>>>(qb, kb, apart);
  smax_k<<<32, 256, 0, stream>>>(apart, qn, kn, attn_scale, Pbuf);
  pv_k<<<dim3(32, AUXBLK), 256, 0, stream>>>(qb, gnbuf, auxv, gminv, gmsv, aminv, amsv, Pbuf, vb, outbb);
  gemm_k<1><<<dim3(8, 576), 256, 0, stream>>>(Wo, img, outbb, nullptr, nullptr, nullptr,
      nullptr, nullptr, bo, nullptr, nullptr, nullptr, xb, nullptr);
  ln_stats_k<<<BLPIX / 256, 256, 0, stream>>>(xb, mu1, rs1);
  gemm_k<2><<<dim3(8, 576), 256, 0, stream>>>(W1, nullptr, nullptr, xb, mu1, rs1,
      gamma_n, beta_n, b1, nullptr, nullptr, nullptr, nullptr, hb);
  gemm_k<3><<<dim3(8, 576), 256, 0, stream>>>(W2, xb, hb, nullptr, nullptr, nullptr,
      nullptr, nullptr, b2, nullptr, nullptr, nullptr, outp, nullptr);
}

// Round 3
// 797.268 us; speedup vs baseline: 2.8209x; 2.8209x over previous
//
#include <hip/hip_runtime.h>
#include <hip/hip_bf16.h>
#include <math.h>

#define BB 4
#define CC 512
#define NHEAD 8
#define HDIM 64
#define NCLS 128
#define DD 768
#define LL 9216
#define BLPIX 36864
#define EPSV 1e-5f
#define GMBLK 144
#define AUXBLK 36
#define LSPLIT 8

typedef __hip_bfloat16 bf16;
typedef __attribute__((ext_vector_type(8))) short short8v;
typedef __attribute__((ext_vector_type(4))) short short4v;
typedef __attribute__((ext_vector_type(4))) float f32x4;

__device__ __forceinline__ float bf2f(bf16 v){ return __bfloat162float(v); }
__device__ __forceinline__ bf16 f2bf(float v){ return __float2bfloat16(v); }
__device__ __forceinline__ short bfbits(float v){ bf16 b = __float2bfloat16(v); return *reinterpret_cast<short*>(&b); }

// ---------------- per-pixel LN stats over C ----------------
__global__ void ln_stats_k(const float* __restrict__ X, float* __restrict__ mu, float* __restrict__ rs){
  int idx = blockIdx.x * blockDim.x + threadIdx.x;
  if (idx >= BLPIX) return;
  int b = idx / LL, l = idx % LL;
  const float* p = X + (size_t)b * CC * LL + l;
  float s = 0.f, ss = 0.f;
  #pragma unroll 8
  for (int c = 0; c < CC; c++){ float v = p[(size_t)c * LL]; s += v; ss += v * v; }
  float m = s * (1.0f / CC);
  float var = ss * (1.0f / CC) - m * m;
  mu[idx] = m; rs[idx] = rsqrtf(var + EPSV);
}

// ---------------- LN-apply + transpose: [b][c][l] fp32 -> [pixel][c] bf16 ----------------
__global__ __launch_bounds__(256) void lnT_k(const float* __restrict__ X,
    const float* __restrict__ mu, const float* __restrict__ rs,
    const float* __restrict__ lng, const float* __restrict__ lnb,
    bf16* __restrict__ out){
  __shared__ float t[64][65];
  int c0 = blockIdx.x * 64;
  int p0 = blockIdx.y * 64;
  int b = p0 / LL;
  int l0 = p0 - b * LL;
  int tid = threadIdx.x;
  #pragma unroll
  for (int i = 0; i < 16; i++){
    int idx = i * 256 + tid;
    int cl = idx >> 6, ll2 = idx & 63;
    t[cl][ll2] = X[(size_t)b * CC * LL + (size_t)(c0 + cl) * LL + l0 + ll2];
  }
  __syncthreads();
  int pr = tid >> 4;
  int cc = (tid & 15) * 4;
  #pragma unroll
  for (int i = 0; i < 4; i++){
    int pl = pr + i * 16;
    int p = p0 + pl;
    float m = mu[p], r = rs[p];
    short4v pk;
    #pragma unroll
    for (int e = 0; e < 4; e++){
      int c = c0 + cc + e;
      float v = (t[cc + e][pl] - m) * r * lng[c] + lnb[c];
      pk[e] = bfbits(v);
    }
    *(short4v*)&out[(size_t)p * CC + c0 + cc] = pk;
  }
}

// ---------------- weights fp32 -> bf16 ----------------
__global__ void wcast_k(const float* __restrict__ wqkv, const float* __restrict__ wo,
                        const float* __restrict__ w1, const float* __restrict__ w2,
                        bf16* __restrict__ oq, bf16* __restrict__ oo,
                        bf16* __restrict__ o1, bf16* __restrict__ o2){
  int i = blockIdx.x * 256 + threadIdx.x;
  int e = i * 4;
  const float* src; bf16* dst; int off;
  if (e < 786432){ src = wqkv; dst = oq; off = e; }
  else if (e < 1048576){ src = wo; dst = oo; off = e - 786432; }
  else if (e < 1310720){ src = w1; dst = o1; off = e - 1048576; }
  else { src = w2; dst = o2; off = e - 1310720; }
  float4 v = *reinterpret_cast<const float4*>(src + off);
  short4v pk;
  pk[0] = bfbits(v.x); pk[1] = bfbits(v.y); pk[2] = bfbits(v.z); pk[3] = bfbits(v.w);
  *(short4v*)&dst[off] = pk;
}

// ---------------- bf16 MFMA GEMM: C[M][N] = A[M][512] @ B[N][512]^T ----------------
// MODE 0: q/k/v bf16 [b][c][l]   MODE 1: d_out = img + C + bo (fp32 [b][c][l])
// MODE 2: h = gelu(C+b1) bf16 [n][c] (pixel-major)   MODE 3: d_out = xb + C + b2
template<int MODE>
__global__ __launch_bounds__(256, 2) void mgemm_k(
    const bf16* __restrict__ A,
    const bf16* __restrict__ B,
    const float* __restrict__ resid,
    const float* __restrict__ bias,
    bf16* __restrict__ qo, bf16* __restrict__ ko, bf16* __restrict__ vo,
    float* __restrict__ xo,
    bf16* __restrict__ ho)
{
  __shared__ short Asm[128 * 64];
  __shared__ short Bsm[128 * 64];
  int tid = threadIdx.x;
  int lane = tid & 63, wv = tid >> 6;
  int wr = wv >> 1, wc = wv & 1;
  int r15 = lane & 15, g = lane >> 4, h7 = lane & 7;
  int m0 = blockIdx.x * 128, n0 = blockIdx.y * 128;
  int srow = tid >> 3, skkg = tid & 7;
  int sslot = ((skkg ^ (srow & 7))) * 8;

  f32x4 acc[4][4];
  #pragma unroll
  for (int i = 0; i < 4; i++)
    #pragma unroll
    for (int j = 0; j < 4; j++) acc[i][j] = (f32x4){0.f, 0.f, 0.f, 0.f};

  short8v pa[4], pb[4];
  auto loadAB = [&](int it){
    int k0 = it * 64;
    #pragma unroll
    for (int r = 0; r < 4; r++){
      pa[r] = *reinterpret_cast<const short8v*>(A + (size_t)(m0 + r * 32 + srow) * 512 + k0 + skkg * 8);
      pb[r] = *reinterpret_cast<const short8v*>(B + (size_t)(n0 + r * 32 + srow) * 512 + k0 + skkg * 8);
    }
  };

  loadAB(0);
  for (int it = 0; it < 8; ++it){
    __syncthreads();
    #pragma unroll
    for (int r = 0; r < 4; r++){
      int row = r * 32 + srow;
      *(short8v*)&Asm[row * 64 + sslot] = pa[r];
      *(short8v*)&Bsm[row * 64 + sslot] = pb[r];
    }
    __syncthreads();
    if (it < 7) loadAB(it + 1);
    #pragma unroll
    for (int s = 0; s < 2; s++){
      int slot = ((s * 4 + g) ^ h7) * 8;
      short8v af[4], bf_[4];
      #pragma unroll
      for (int i = 0; i < 4; i++){
        af[i]  = *(const short8v*)&Asm[(wr * 64 + i * 16 + r15) * 64 + slot];
        bf_[i] = *(const short8v*)&Bsm[(wc * 64 + i * 16 + r15) * 64 + slot];
      }
      #pragma unroll
      for (int i = 0; i < 4; i++)
        #pragma unroll
        for (int j = 0; j < 4; j++){
          if (MODE == 2)
            acc[i][j] = __builtin_amdgcn_mfma_f32_16x16x32_bf16(bf_[i], af[j], acc[i][j], 0, 0, 0);
          else
            acc[i][j] = __builtin_amdgcn_mfma_f32_16x16x32_bf16(af[i], bf_[j], acc[i][j], 0, 0, 0);
        }
    }
  }

  int bIdx = n0 / LL;
  int lbase = n0 - bIdx * LL;
  if (MODE == 0){
    int part = m0 >> 9;
    bf16* dst = (part == 0) ? qo : ((part == 1) ? ko : vo);
    int chb = (m0 & 511) + wr * 64;
    #pragma unroll
    for (int i = 0; i < 4; i++)
      #pragma unroll
      for (int j = 0; j < 4; j++){
        int l = lbase + wc * 64 + j * 16 + r15;
        #pragma unroll
        for (int e = 0; e < 4; e++){
          int ch = chb + i * 16 + g * 4 + e;
          dst[(size_t)bIdx * CC * LL + (size_t)ch * LL + l] = f2bf(acc[i][j][e]);
        }
      }
  } else if (MODE == 1 || MODE == 3){
    #pragma unroll
    for (int i = 0; i < 4; i++)
      #pragma unroll
      for (int j = 0; j < 4; j++){
        int l = lbase + wc * 64 + j * 16 + r15;
        #pragma unroll
        for (int e = 0; e < 4; e++){
          int m = m0 + wr * 64 + i * 16 + g * 4 + e;
          size_t o = (size_t)bIdx * CC * LL + (size_t)m * LL + l;
          xo[o] = resid[o] + acc[i][j][e] + bias[m];
        }
      }
  } else {
    #pragma unroll
    for (int i = 0; i < 4; i++)
      #pragma unroll
      for (int j = 0; j < 4; j++){
        int mm = m0 + wr * 64 + j * 16 + r15;
        float bv = bias[mm];
        #pragma unroll
        for (int e = 0; e < 4; e++){
          int n = n0 + wc * 64 + i * 16 + g * 4 + e;
          float t = acc[i][j][e] + bv;
          float gv = 0.5f * t * (1.0f + erff(t * 0.70710678118654752f));
          ho[(size_t)n * CC + mm] = f2bf(gv);
        }
      }
  }
}

// ---------------- per-(b,h,d) L2 norm over L for q and k ----------------
__global__ void rownorm_k(const bf16* __restrict__ q, const bf16* __restrict__ k,
                          float* __restrict__ qn, float* __restrict__ kn){
  __shared__ float red[256];
  int row = blockIdx.x;
  const bf16* src = (row < 2048) ? q : k;
  int r = (row < 2048) ? row : row - 2048;
  const bf16* p = src + (size_t)r * LL;
  float s = 0.f;
  for (int i = threadIdx.x; i < LL; i += 256){ float v = bf2f(p[i]); s += v * v; }
  red[threadIdx.x] = s; __syncthreads();
  for (int st = 128; st > 0; st >>= 1){ if (threadIdx.x < st) red[threadIdx.x] += red[threadIdx.x + st]; __syncthreads(); }
  if (threadIdx.x == 0){
    float nv = fmaxf(sqrtf(red[0]), 1e-12f);
    if (row < 2048) qn[r] = nv; else kn[r] = nv;
  }
}

__global__ void clsg_k(const float* __restrict__ cls_embs, const float* __restrict__ gamma_g,
                       const float* __restrict__ beta_g, const float* __restrict__ Wg,
                       float* __restrict__ g, float* __restrict__ gn){
  __shared__ float cn[DD];
  __shared__ float red[256];
  __shared__ float gsh[CC];
  __shared__ float nrm[NHEAD];
  int n = blockIdx.x;
  const float* e = cls_embs + (size_t)n * DD;
  float s = 0.f, ss = 0.f;
  for (int i = threadIdx.x; i < DD; i += 256){ float v = e[i]; s += v; ss += v * v; }
  red[threadIdx.x] = s; __syncthreads();
  for (int st = 128; st > 0; st >>= 1){ if (threadIdx.x < st) red[threadIdx.x] += red[threadIdx.x + st]; __syncthreads(); }
  float mean = red[0] / DD; __syncthreads();
  red[threadIdx.x] = ss; __syncthreads();
  for (int st = 128; st > 0; st >>= 1){ if (threadIdx.x < st) red[threadIdx.x] += red[threadIdx.x + st]; __syncthreads(); }
  float var = red[0] / DD - mean * mean;
  float rstd = rsqrtf(var + EPSV);
  __syncthreads();
  for (int i = threadIdx.x; i < DD; i += 256) cn[i] = (e[i] - mean) * rstd * gamma_g[i] + beta_g[i];
  __syncthreads();
  for (int c = threadIdx.x; c < CC; c += 256){
    const float* w = Wg + (size_t)c * DD;
    float a = 0.f;
    #pragma unroll 8
    for (int d = 0; d < DD; d++) a += cn[d] * w[d];
    gsh[c] = a;
  }
  __syncthreads();
  if (threadIdx.x < NHEAD){
    float a = 0.f;
    for (int d = 0; d < HDIM; d++){ float v = gsh[threadIdx.x * HDIM + d]; a += v * v; }
    nrm[threadIdx.x] = fmaxf(sqrtf(a), 1e-12f);
  }
  __syncthreads();
  for (int c = threadIdx.x; c < CC; c += 256){
    g[(size_t)n * CC + c] = gsh[c];
    gn[(size_t)n * CC + c] = gsh[c] / nrm[c >> 6];
  }
}

__global__ void clsobj_k(const float* __restrict__ g, const float* __restrict__ cls_l,
                         float* __restrict__ cls_obj){
  int idx = blockIdx.x * 256 + threadIdx.x;
  if (idx >= BB * CC) return;
  int b = idx >> 9, c = idx & 511;
  float a = 0.f;
  for (int n = 0; n < NCLS; n++) a += g[(size_t)n * CC + c] * cls_l[b * NCLS + n];
  cls_obj[idx] = a;
}

__global__ __launch_bounds__(256) void gm1_k(const bf16* __restrict__ q, const float* __restrict__ gn,
        float* __restrict__ pmin, float* __restrict__ pmax){
  __shared__ float smem[12800];
  float* qs = smem;
  float* gns = smem + 4352;
  float* rnorm = smem + 4352 + 8320;
  float* rmin = smem;
  float* rmax = smem + 2048;
  int bh = blockIdx.x;
  int lt = blockIdx.y;
  int l0 = lt * 64;
  int tid = threadIdx.x;
  int b = bh >> 3, h = bh & 7;
  const bf16* qp = q + (size_t)b * CC * LL + (size_t)h * HDIM * LL + l0;
  #pragma unroll
  for (int i = 0; i < 16; i++){
    int idx = tid + i * 256;
    int d = idx >> 6, ll = idx & 63;
    qs[d * 68 + ll] = bf2f(qp[(size_t)d * LL + ll]);
  }
  #pragma unroll
  for (int i = 0; i < 32; i++){
    int idx = tid + i * 256;
    int n = idx >> 6, d = idx & 63;
    gns[n * 65 + d] = gn[(size_t)n * CC + h * HDIM + d];
  }
  __syncthreads();
  if (tid < 64){
    float s = 0.f;
    for (int d = 0; d < 64; d++){ float v = qs[d * 68 + tid]; s += v * v; }
    rnorm[tid] = 1.0f / fmaxf(sqrtf(s), 1e-12f);
  }
  __syncthreads();
  int tx = tid & 15, ty = tid >> 4;
  float acc[8][4] = {};
  for (int d = 0; d < 64; d++){
    float qv[4], gv[8];
    #pragma unroll
    for (int j = 0; j < 4; j++) qv[j] = qs[d * 68 + tx * 4 + j];
    #pragma unroll
    for (int i = 0; i < 8; i++) gv[i] = gns[(ty * 8 + i) * 65 + d];
    #pragma unroll
    for (int i = 0; i < 8; i++)
      #pragma unroll
      for (int j = 0; j < 4; j++) acc[i][j] += gv[i] * qv[j];
  }
  __syncthreads();
  float tmn[8], tmx[8];
  #pragma unroll
  for (int i = 0; i < 8; i++){
    float mn = 1e30f, mx = -1e30f;
    #pragma unroll
    for (int j = 0; j < 4; j++){
      int l = tx * 4 + j;
      float v = acc[i][j] * rnorm[l];
      mn = fminf(mn, v); mx = fmaxf(mx, v);
    }
    tmn[i] = mn; tmx[i] = mx;
  }
  #pragma unroll
  for (int i = 0; i < 8; i++){
    int n = ty * 8 + i;
    rmin[n * 16 + tx] = tmn[i];
    rmax[n * 16 + tx] = tmx[i];
  }
  __syncthreads();
  if (tid < 128){
    float mn = 1e30f, mx = -1e30f;
    #pragma unroll
    for (int t = 0; t < 16; t++){ mn = fminf(mn, rmin[tid * 16 + t]); mx = fmaxf(mx, rmax[tid * 16 + t]); }
    pmin[((size_t)bh * 128 + tid) * GMBLK + lt] = mn;
    pmax[((size_t)bh * 128 + tid) * GMBLK + lt] = mx;
  }
}

__global__ void gmred_k(const float* __restrict__ pmin, const float* __restrict__ pmax,
                        float* __restrict__ gmin, float* __restrict__ gms){
  __shared__ float rmn[64], rmx[64];
  int row = blockIdx.x;
  float mn = 1e30f, mx = -1e30f;
  for (int i = threadIdx.x; i < GMBLK; i += 64){
    mn = fminf(mn, pmin[(size_t)row * GMBLK + i]);
    mx = fmaxf(mx, pmax[(size_t)row * GMBLK + i]);
  }
  rmn[threadIdx.x] = mn; rmx[threadIdx.x] = mx; __syncthreads();
  for (int st = 32; st > 0; st >>= 1){
    if (threadIdx.x < st){
      rmn[threadIdx.x] = fminf(rmn[threadIdx.x], rmn[threadIdx.x + st]);
      rmx[threadIdx.x] = fmaxf(rmx[threadIdx.x], rmx[threadIdx.x + st]);
    }
    __syncthreads();
  }
  if (threadIdx.x == 0){ gmin[row] = rmn[0]; gms[row] = rmx[0] - rmn[0]; }
}

__global__ void seg_k(const float* __restrict__ seg, const bf16* __restrict__ k, float* __restrict__ seg_num){
  __shared__ float red[256];
  int bc = blockIdx.x;
  int b = bc >> 9;
  const bf16* p = k + (size_t)bc * LL;
  const float* sp = seg + (size_t)b * LL;
  float s = 0.f;
  for (int i = threadIdx.x; i < LL; i += 256){
    float m = 1.0f / (1.0f + expf(-sp[i]));
    s += m * bf2f(p[i]);
  }
  red[threadIdx.x] = s; __syncthreads();
  for (int st = 128; st > 0; st >>= 1){ if (threadIdx.x < st) red[threadIdx.x] += red[threadIdx.x + st]; __syncthreads(); }
  if (threadIdx.x == 0) seg_num[bc] = red[0];
}

__global__ void segden_k(const float* __restrict__ seg, float* __restrict__ den){
  __shared__ float red[256];
  int b = blockIdx.x;
  const float* sp = seg + (size_t)b * LL;
  float s = 0.f;
  for (int i = threadIdx.x; i < LL; i += 256) s += 1.0f / (1.0f + expf(-sp[i]));
  red[threadIdx.x] = s; __syncthreads();
  for (int st = 128; st > 0; st >>= 1){ if (threadIdx.x < st) red[threadIdx.x] += red[threadIdx.x + st]; __syncthreads(); }
  if (threadIdx.x == 0) den[b] = red[0];
}

__global__ void obj_k(const float* __restrict__ cls_obj, const float* __restrict__ seg_num,
                      const float* __restrict__ den, float* __restrict__ obj){
  __shared__ float sval[2048];
  __shared__ float nrm[32];
  int tid = threadIdx.x;
  #pragma unroll
  for (int i = 0; i < 8; i++){
    int idx = tid + i * 256;
    int b = idx >> 9;
    sval[idx] = cls_obj[idx] + seg_num[idx] / den[b];
  }
  __syncthreads();
  if (tid < 32){
    float s = 0.f;
    for (int d = 0; d < 64; d++){ float v = sval[tid * 64 + d]; s += v * v; }
    nrm[tid] = fmaxf(sqrtf(s), 1e-12f);
  }
  __syncthreads();
  #pragma unroll
  for (int i = 0; i < 8; i++){
    int idx = tid + i * 256;
    obj[idx] = sval[idx] / nrm[idx >> 6];
  }
}

__global__ void aux_k(const bf16* __restrict__ k, const float* __restrict__ obj, float* __restrict__ aux,
                      float* __restrict__ pmin, float* __restrict__ pmax){
  __shared__ float os[64];
  __shared__ float rmn[256], rmx[256];
  int bh = blockIdx.x, lt = blockIdx.y;
  int b = bh >> 3, h = bh & 7;
  int l = lt * 256 + threadIdx.x;
  if (threadIdx.x < 64) os[threadIdx.x] = obj[bh * 64 + threadIdx.x];
  __syncthreads();
  const bf16* kp = k + (size_t)b * CC * LL + (size_t)h * HDIM * LL + l;
  float ss = 0.f, dot = 0.f;
  #pragma unroll 8
  for (int d = 0; d < 64; d++){ float v = bf2f(kp[(size_t)d * LL]); ss += v * v; dot += os[d] * v; }
  float av = dot / fmaxf(sqrtf(ss), 1e-12f);
  aux[(size_t)bh * LL + l] = av;
  rmn[threadIdx.x] = av; rmx[threadIdx.x] = av; __syncthreads();
  for (int st = 128; st > 0; st >>= 1){
    if (threadIdx.x < st){
      rmn[threadIdx.x] = fminf(rmn[threadIdx.x], rmn[threadIdx.x + st]);
      rmx[threadIdx.x] = fmaxf(rmx[threadIdx.x], rmx[threadIdx.x + st]);
    }
    __syncthreads();
  }
  if (threadIdx.x == 0){ pmin[bh * AUXBLK + lt] = rmn[0]; pmax[bh * AUXBLK + lt] = rmx[0]; }
}

__global__ void auxred_k(const float* __restrict__ pmin, const float* __restrict__ pmax,
                         float* __restrict__ amin, float* __restrict__ ams){
  __shared__ float rmn[64], rmx[64];
  int bh = blockIdx.x;
  float mn = 1e30f, mx = -1e30f;
  for (int i = threadIdx.x; i < AUXBLK; i += 64){
    mn = fminf(mn, pmin[bh * AUXBLK + i]);
    mx = fmaxf(mx, pmax[bh * AUXBLK + i]);
  }
  rmn[threadIdx.x] = mn; rmx[threadIdx.x] = mx; __syncthreads();
  for (int st = 32; st > 0; st >>= 1){
    if (threadIdx.x < st){
      rmn[threadIdx.x] = fminf(rmn[threadIdx.x], rmn[threadIdx.x + st]);
      rmx[threadIdx.x] = fmaxf(rmx[threadIdx.x], rmx[threadIdx.x + st]);
    }
    __syncthreads();
  }
  if (threadIdx.x == 0){ amin[bh] = rmn[0]; ams[bh] = rmx[0] - rmn[0]; }
}

__global__ __launch_bounds__(256) void attn_k(const bf16* __restrict__ q, const bf16* __restrict__ k,
                                              float* __restrict__ part){
  __shared__ float qs[64 * 68];
  __shared__ float ks[64 * 68];
  int ls = blockIdx.x, bh = blockIdx.y;
  int b = bh >> 3, h = bh & 7;
  int tid = threadIdx.x, tx = tid & 15, ty = tid >> 4;
  const bf16* qp = q + (size_t)b * CC * LL + (size_t)h * HDIM * LL;
  const bf16* kp = k + (size_t)b * CC * LL + (size_t)h * HDIM * LL;
  float acc[4][4] = {};
  for (int lt = ls * 18; lt < (ls + 1) * 18; lt++){
    int l0 = lt * 64;
    #pragma unroll
    for (int i = 0; i < 16; i++){
      int idx = tid + i * 256;
      int d = idx >> 6, ll = idx & 63;
      qs[d * 68 + ll] = bf2f(qp[(size_t)d * LL + l0 + ll]);
      ks[d * 68 + ll] = bf2f(kp[(size_t)d * LL + l0 + ll]);
    }
    __syncthreads();
    for (int ll = 0; ll < 64; ll++){
      float qv[4], kv[4];
      #pragma unroll
      for (int i = 0; i < 4; i++) qv[i] = qs[(ty * 4 + i) * 68 + ll];
      #pragma unroll
      for (int j = 0; j < 4; j++) kv[j] = ks[(tx * 4 + j) * 68 + ll];
      #pragma unroll
      for (int i = 0; i < 4; i++)
        #pragma unroll
        for (int j = 0; j < 4; j++) acc[i][j] += qv[i] * kv[j];
    }
    __syncthreads();
  }
  #pragma unroll
  for (int i = 0; i < 4; i++)
    #pragma unroll
    for (int j = 0; j < 4; j++){
      int d = ty * 4 + i, e = tx + 16 * j;
      part[((size_t)(bh * LSPLIT + ls)) * 4096 + d * 64 + e] = acc[i][j];
    }
}

__global__ void smax_k(const float* __restrict__ part, const float* __restrict__ qn,
                       const float* __restrict__ kn, const float* __restrict__ scale,
                       float* __restrict__ P){
  __shared__ float As[64 * 65];
  int bh = blockIdx.x;
  int h = bh & 7;
  int tid = threadIdx.x;
  #pragma unroll
  for (int i = 0; i < 16; i++){
    int cell = tid + i * 256;
    int d = cell >> 6, e = cell & 63;
    float s = 0.f;
    #pragma unroll
    for (int ls = 0; ls < LSPLIT; ls++) s += part[((size_t)(bh * LSPLIT + ls)) * 4096 + cell];
    As[d * 65 + e] = s * scale[h] / (qn[bh * 64 + d] * kn[bh * 64 + e]);
  }
  __syncthreads();
  if (tid < 64){
    int d = tid;
    float mx = -1e30f;
    for (int e = 0; e < 64; e++) mx = fmaxf(mx, As[d * 65 + e]);
    float sum = 0.f;
    for (int e = 0; e < 64; e++){ float ev = expf(As[d * 65 + e] - mx); As[d * 65 + e] = ev; sum += ev; }
    float inv = 1.0f / sum;
    for (int e = 0; e < 64; e++) P[(size_t)bh * 4096 + d * 64 + e] = As[d * 65 + e] * inv;
  }
}

// pv: recompute gm from q&gn, combine with aux, P @ (gm*v) -> outT [pixel][c] bf16
__global__ __launch_bounds__(256) void pv_k(const bf16* __restrict__ q, const float* __restrict__ gn_all,
      const float* __restrict__ aux,
      const float* __restrict__ gmin, const float* __restrict__ gms,
      const float* __restrict__ amin, const float* __restrict__ ams,
      const float* __restrict__ P, const bf16* __restrict__ v, bf16* __restrict__ outT){
  __shared__ float Ps[4096];
  __shared__ float gns[8192];
  __shared__ float gmins[128], gmss[128];
  int bh = blockIdx.x, lt = blockIdx.y;
  int b = bh >> 3, h = bh & 7;
  int tid = threadIdx.x;
  int l = lt * 256 + tid;
  #pragma unroll
  for (int i = 0; i < 16; i++) Ps[tid + i * 256] = P[(size_t)bh * 4096 + tid + i * 256];
  #pragma unroll
  for (int i = 0; i < 32; i++){
    int idx = tid + i * 256;
    gns[idx] = gn_all[(size_t)(idx >> 6) * CC + h * HDIM + (idx & 63)];
  }
  if (tid < 128){ gmins[tid] = gmin[bh * 128 + tid]; gmss[tid] = gms[bh * 128 + tid]; }
  __syncthreads();
  const bf16* qp = q + (size_t)b * CC * LL + (size_t)h * HDIM * LL + l;
  float val[64];
  float ss = 0.f;
  #pragma unroll
  for (int d = 0; d < 64; d++){ float qv = bf2f(qp[(size_t)d * LL]); val[d] = qv; ss += qv * qv; }
  float rq = 1.0f / fmaxf(sqrtf(ss), 1e-12f);
  #pragma unroll
  for (int d = 0; d < 64; d++) val[d] *= rq;
  float se = 0.f, set = 0.f;
  for (int n = 0; n < 128; n++){
    float dot = 0.f;
    #pragma unroll
    for (int d = 0; d < 64; d++) dot += gns[n * 64 + d] * val[d];
    float t = (dot - gmins[n]) / gmss[n];
    float e = expf(t);
    se += e; set += e * t;
  }
  float gmred = set / se;
  float auxn = (aux[(size_t)bh * LL + l] - amin[bh]) / ams[bh];
  float gmf = gmred * auxn;
  const bf16* vp = v + (size_t)b * CC * LL + (size_t)h * HDIM * LL + l;
  #pragma unroll
  for (int e2 = 0; e2 < 64; e2++) val[e2] = gmf * bf2f(vp[(size_t)e2 * LL]);
  bf16* op = outT + ((size_t)(b * LL + l)) * CC + h * 64;
  for (int d4 = 0; d4 < 16; ++d4){
    short4v pk;
    #pragma unroll
    for (int e = 0; e < 4; ++e){
      int d = d4 * 4 + e;
      float a = 0.f;
      #pragma unroll
      for (int e2 = 0; e2 < 64; e2++) a += Ps[d * 64 + e2] * val[e2];
      pk[e] = bfbits(a);
    }
    *(short4v*)&op[d4 * 4] = pk;
  }
}

extern "C" void kernel_launch(void* const* d_in, const int* in_sizes, int n_in,
                              void* d_out, int out_size, void* d_ws, size_t ws_size,
                              hipStream_t stream){
  const float* img        = (const float*)d_in[0];
  const float* cls_embs   = (const float*)d_in[1];
  const float* cls_logits = (const float*)d_in[2];
  const float* seg        = (const float*)d_in[3];
  const float* gamma_g    = (const float*)d_in[4];
  const float* beta_g     = (const float*)d_in[5];
  const float* gamma_f    = (const float*)d_in[6];
  const float* beta_f     = (const float*)d_in[7];
  const float* attn_scale = (const float*)d_in[8];
  const float* Wg         = (const float*)d_in[9];
  const float* Wqkv       = (const float*)d_in[10];
  const float* Wo         = (const float*)d_in[11];
  const float* bo         = (const float*)d_in[12];
  const float* gamma_n    = (const float*)d_in[13];
  const float* beta_n     = (const float*)d_in[14];
  const float* W1         = (const float*)d_in[15];
  const float* b1         = (const float*)d_in[16];
  const float* W2         = (const float*)d_in[17];
  const float* b2         = (const float*)d_in[18];
  float* outp = (float*)d_out;
  (void)in_sizes; (void)n_in; (void)out_size;

  char* wsb = (char*)d_ws;
  size_t off = 0;
  auto alloc = [&](size_t bytes)->char*{
    char* p = wsb + off;
    off += (bytes + 255) & ~(size_t)255;
    return p;
  };
  float* mu1   = (float*)alloc((size_t)BLPIX * 4);
  float* rs1   = (float*)alloc((size_t)BLPIX * 4);
  float* qn    = (float*)alloc(2048 * 4);
  float* kn    = (float*)alloc(2048 * 4);
  float* gbuf  = (float*)alloc((size_t)NCLS * CC * 4);
  float* gnbuf = (float*)alloc((size_t)NCLS * CC * 4);
  float* clsov = (float*)alloc(2048 * 4);
  float* segn  = (float*)alloc(2048 * 4);
  float* segd  = (float*)alloc(256);
  float* objv  = (float*)alloc(2048 * 4);
  float* gminp = (float*)alloc((size_t)32 * 128 * GMBLK * 4);
  float* gmaxp = (float*)alloc((size_t)32 * 128 * GMBLK * 4);
  float* gminv = (float*)alloc(4096 * 4);
  float* gmsv  = (float*)alloc(4096 * 4);
  float* auxv  = (float*)alloc((size_t)32 * LL * 4);
  float* apmin = (float*)alloc(32 * AUXBLK * 4);
  float* apmax = (float*)alloc(32 * AUXBLK * 4);
  float* aminv = (float*)alloc(256);
  float* amsv  = (float*)alloc(256);
  float* Pbuf  = (float*)alloc((size_t)32 * 4096 * 4);
  float* apart = (float*)alloc((size_t)32 * LSPLIT * 4096 * 4);
  bf16* qb    = (bf16*)alloc((size_t)BB * CC * LL * 2);
  bf16* kb    = (bf16*)alloc((size_t)BB * CC * LL * 2);
  bf16* wqkvb = (bf16*)alloc((size_t)1536 * 512 * 2);
  bf16* wob   = (bf16*)alloc((size_t)512 * 512 * 2);
  bf16* w1b   = (bf16*)alloc((size_t)512 * 512 * 2);
  bf16* w2b   = (bf16*)alloc((size_t)512 * 512 * 2);
  // d_out partitioning (bf16 halves), lifetimes end before Wo-GEMM writes x into d_out:
  bf16* vb  = (bf16*)d_out;                                       // v [b][c][l]
  bf16* xnT = (bf16*)((char*)d_out + (size_t)BB * CC * LL * 2);   // LN(img)^T [pixel][c]
  // ws aliases (disjoint lifetimes):
  bf16* outT = kb;   // attention output [pixel][c] (k dead after attn/aux/seg)
  bf16* xnT2 = qb;   // LN(x)^T (q dead after pv_k)
  bf16* hbT  = kb;   // MLP hidden [pixel][c] (outT dead after Wo-GEMM)
  float* xb  = outp; // x fp32 in d_out from Wo-GEMM onward
  if (off > ws_size) return;

  ln_stats_k<<<BLPIX / 256, 256, 0, stream>>>(img, mu1, rs1);
  wcast_k<<<1536, 256, 0, stream>>>(Wqkv, Wo, W1, W2, wqkvb, wob, w1b, w2b);
  lnT_k<<<dim3(8, 576), 256, 0, stream>>>(img, mu1, rs1, gamma_f, beta_f, xnT);
  mgemm_k<0><<<dim3(12, 288), 256, 0, stream>>>(wqkvb, xnT, nullptr, nullptr,
      qb, kb, vb, nullptr, nullptr);
  rownorm_k<<<4096, 256, 0, stream>>>(qb, kb, qn, kn);
  clsg_k<<<NCLS, 256, 0, stream>>>(cls_embs, gamma_g, beta_g, Wg, gbuf, gnbuf);
  clsobj_k<<<8, 256, 0, stream>>>(gbuf, cls_logits, clsov);
  gm1_k<<<dim3(32, GMBLK), 256, 0, stream>>>(qb, gnbuf, gminp, gmaxp);
  gmred_k<<<4096, 64, 0, stream>>>(gminp, gmaxp, gminv, gmsv);
  seg_k<<<2048, 256, 0, stream>>>(seg, kb, segn);
  segden_k<<<BB, 256, 0, stream>>>(seg, segd);
  obj_k<<<1, 256, 0, stream>>>(clsov, segn, segd, objv);
  aux_k<<<dim3(32, AUXBLK), 256, 0, stream>>>(kb, objv, auxv, apmin, apmax);
  auxred_k<<<32, 64, 0, stream>>>(apmin, apmax, aminv, amsv);
  attn_k<<<dim3(LSPLIT, 32), 256, 0, stream>>>(qb, kb, apart);
  smax_k<<<32, 256, 0, stream>>>(apart, qn, kn, attn_scale, Pbuf);
  pv_k<<<dim3(32, AUXBLK), 256, 0, stream>>>(qb, gnbuf, auxv, gminv, gmsv, aminv, amsv, Pbuf, vb, outT);
  mgemm_k<1><<<dim3(4, 288), 256, 0, stream>>>(wob, outT, img, bo,
      nullptr, nullptr, nullptr, xb, nullptr);
  ln_stats_k<<<BLPIX / 256, 256, 0, stream>>>(xb, mu1, rs1);
  lnT_k<<<dim3(8, 576), 256, 0, stream>>>(xb, mu1, rs1, gamma_n, beta_n, xnT2);
  mgemm_k<2><<<dim3(4, 288), 256, 0, stream>>>(w1b, xnT2, nullptr, b1,
      nullptr, nullptr, nullptr, nullptr, hbT);
  mgemm_k<3><<<dim3(4, 288), 256, 0, stream>>>(w2b, hbT, xb, b2,
      nullptr, nullptr, nullptr, outp, nullptr);
}

// Round 4
// 540.464 us; speedup vs baseline: 4.1613x; 1.4752x over previous
//
#include <hip/hip_runtime.h>
#include <hip/hip_bf16.h>
#include <math.h>

#define BB 4
#define CC 512
#define NHEAD 8
#define HDIM 64
#define NCLS 128
#define DD 768
#define LL 9216
#define BLPIX 36864
#define EPSV 1e-5f
#define GMBLK 144
#define AUXBLK 36
#define LSPLIT 8

typedef __hip_bfloat16 bf16;
typedef __attribute__((ext_vector_type(8))) short short8v;
typedef __attribute__((ext_vector_type(4))) short short4v;
typedef __attribute__((ext_vector_type(4))) float f32x4;

__device__ __forceinline__ float bf2f(bf16 v){ return __bfloat162float(v); }
__device__ __forceinline__ bf16 f2bf(float v){ return __float2bfloat16(v); }
__device__ __forceinline__ short bfbits(float v){ bf16 b = __float2bfloat16(v); return *reinterpret_cast<short*>(&b); }

// ---------------- per-pixel LN stats over C ----------------
__global__ void ln_stats_k(const float* __restrict__ X, float* __restrict__ mu, float* __restrict__ rs){
  int idx = blockIdx.x * blockDim.x + threadIdx.x;
  if (idx >= BLPIX) return;
  int b = idx / LL, l = idx % LL;
  const float* p = X + (size_t)b * CC * LL + l;
  float s = 0.f, ss = 0.f;
  #pragma unroll 8
  for (int c = 0; c < CC; c++){ float v = p[(size_t)c * LL]; s += v; ss += v * v; }
  float m = s * (1.0f / CC);
  float var = ss * (1.0f / CC) - m * m;
  mu[idx] = m; rs[idx] = rsqrtf(var + EPSV);
}

// ---------------- LN-apply + transpose: [b][c][l] fp32 -> [pixel][c] bf16 ----------------
__global__ __launch_bounds__(256) void lnT_k(const float* __restrict__ X,
    const float* __restrict__ mu, const float* __restrict__ rs,
    const float* __restrict__ lng, const float* __restrict__ lnb,
    bf16* __restrict__ out){
  __shared__ float t[64][65];
  int c0 = blockIdx.x * 64;
  int p0 = blockIdx.y * 64;
  int b = p0 / LL;
  int l0 = p0 - b * LL;
  int tid = threadIdx.x;
  #pragma unroll
  for (int i = 0; i < 16; i++){
    int idx = i * 256 + tid;
    int cl = idx >> 6, ll2 = idx & 63;
    t[cl][ll2] = X[(size_t)b * CC * LL + (size_t)(c0 + cl) * LL + l0 + ll2];
  }
  __syncthreads();
  int pr = tid >> 4;
  int cc = (tid & 15) * 4;
  #pragma unroll
  for (int i = 0; i < 4; i++){
    int pl = pr + i * 16;
    int p = p0 + pl;
    float m = mu[p], r = rs[p];
    short4v pk;
    #pragma unroll
    for (int e = 0; e < 4; e++){
      int c = c0 + cc + e;
      float v = (t[cc + e][pl] - m) * r * lng[c] + lnb[c];
      pk[e] = bfbits(v);
    }
    *(short4v*)&out[(size_t)p * CC + c0 + cc] = pk;
  }
}

// ---------------- weights fp32 -> bf16 ----------------
__global__ void wcast_k(const float* __restrict__ wqkv, const float* __restrict__ wo,
                        const float* __restrict__ w1, const float* __restrict__ w2,
                        bf16* __restrict__ oq, bf16* __restrict__ oo,
                        bf16* __restrict__ o1, bf16* __restrict__ o2){
  int i = blockIdx.x * 256 + threadIdx.x;
  int e = i * 4;
  const float* src; bf16* dst; int off;
  if (e < 786432){ src = wqkv; dst = oq; off = e; }
  else if (e < 1048576){ src = wo; dst = oo; off = e - 786432; }
  else if (e < 1310720){ src = w1; dst = o1; off = e - 1048576; }
  else { src = w2; dst = o2; off = e - 1310720; }
  float4 v = *reinterpret_cast<const float4*>(src + off);
  short4v pk;
  pk[0] = bfbits(v.x); pk[1] = bfbits(v.y); pk[2] = bfbits(v.z); pk[3] = bfbits(v.w);
  *(short4v*)&dst[off] = pk;
}

// ---------------- bf16 MFMA GEMM: C[M][N] = A[M][512] @ B[N][512]^T ----------------
// MODE 0: q/k [b][c][l] bf16, v -> vT [pixel][c] bf16
// MODE 1: d_out = img + C + bo (fp32 [b][c][l])
// MODE 2: h = gelu(C+b1) bf16 [pixel][c]   MODE 3: d_out = xb + C + b2
template<int MODE>
__global__ __launch_bounds__(256, 2) void mgemm_k(
    const bf16* __restrict__ A,
    const bf16* __restrict__ B,
    const float* __restrict__ resid,
    const float* __restrict__ bias,
    bf16* __restrict__ qo, bf16* __restrict__ ko, bf16* __restrict__ vo,
    float* __restrict__ xo,
    bf16* __restrict__ ho)
{
  __shared__ short Asm[128 * 64];
  __shared__ short Bsm[128 * 64];
  int tid = threadIdx.x;
  int lane = tid & 63, wv = tid >> 6;
  int wr = wv >> 1, wc = wv & 1;
  int r15 = lane & 15, g = lane >> 4, h7 = lane & 7;
  int m0 = blockIdx.x * 128, n0 = blockIdx.y * 128;
  int srow = tid >> 3, skkg = tid & 7;
  int sslot = ((skkg ^ (srow & 7))) * 8;

  f32x4 acc[4][4];
  #pragma unroll
  for (int i = 0; i < 4; i++)
    #pragma unroll
    for (int j = 0; j < 4; j++) acc[i][j] = (f32x4){0.f, 0.f, 0.f, 0.f};

  short8v pa[4], pb[4];
  auto loadAB = [&](int it){
    int k0 = it * 64;
    #pragma unroll
    for (int r = 0; r < 4; r++){
      pa[r] = *reinterpret_cast<const short8v*>(A + (size_t)(m0 + r * 32 + srow) * 512 + k0 + skkg * 8);
      pb[r] = *reinterpret_cast<const short8v*>(B + (size_t)(n0 + r * 32 + srow) * 512 + k0 + skkg * 8);
    }
  };

  loadAB(0);
  for (int it = 0; it < 8; ++it){
    __syncthreads();
    #pragma unroll
    for (int r = 0; r < 4; r++){
      int row = r * 32 + srow;
      *(short8v*)&Asm[row * 64 + sslot] = pa[r];
      *(short8v*)&Bsm[row * 64 + sslot] = pb[r];
    }
    __syncthreads();
    if (it < 7) loadAB(it + 1);
    #pragma unroll
    for (int s = 0; s < 2; s++){
      int slot = ((s * 4 + g) ^ h7) * 8;
      short8v af[4], bf_[4];
      #pragma unroll
      for (int i = 0; i < 4; i++){
        af[i]  = *(const short8v*)&Asm[(wr * 64 + i * 16 + r15) * 64 + slot];
        bf_[i] = *(const short8v*)&Bsm[(wc * 64 + i * 16 + r15) * 64 + slot];
      }
      #pragma unroll
      for (int i = 0; i < 4; i++)
        #pragma unroll
        for (int j = 0; j < 4; j++){
          if (MODE == 2)
            acc[i][j] = __builtin_amdgcn_mfma_f32_16x16x32_bf16(bf_[i], af[j], acc[i][j], 0, 0, 0);
          else
            acc[i][j] = __builtin_amdgcn_mfma_f32_16x16x32_bf16(af[i], bf_[j], acc[i][j], 0, 0, 0);
        }
    }
  }

  int bIdx = n0 / LL;
  int lbase = n0 - bIdx * LL;
  if (MODE == 0){
    int part = m0 >> 9;
    if (part < 2){
      bf16* dst = (part == 0) ? qo : ko;
      int chb = (m0 & 511) + wr * 64;
      #pragma unroll
      for (int i = 0; i < 4; i++)
        #pragma unroll
        for (int j = 0; j < 4; j++){
          int l = lbase + wc * 64 + j * 16 + r15;
          #pragma unroll
          for (int e = 0; e < 4; e++){
            int ch = chb + i * 16 + g * 4 + e;
            dst[(size_t)bIdx * CC * LL + (size_t)ch * LL + l] = f2bf(acc[i][j][e]);
          }
        }
    } else {
      // v -> vT [pixel][c]
      int chb = (m0 & 511) + wr * 64;
      #pragma unroll
      for (int i = 0; i < 4; i++)
        #pragma unroll
        for (int j = 0; j < 4; j++){
          int l = lbase + wc * 64 + j * 16 + r15;
          int ch = chb + i * 16 + g * 4;
          short4v pk;
          #pragma unroll
          for (int e = 0; e < 4; e++) pk[e] = bfbits(acc[i][j][e]);
          *(short4v*)&vo[((size_t)bIdx * LL + l) * CC + ch] = pk;
        }
    }
  } else if (MODE == 1 || MODE == 3){
    #pragma unroll
    for (int i = 0; i < 4; i++)
      #pragma unroll
      for (int j = 0; j < 4; j++){
        int l = lbase + wc * 64 + j * 16 + r15;
        #pragma unroll
        for (int e = 0; e < 4; e++){
          int m = m0 + wr * 64 + i * 16 + g * 4 + e;
          size_t o = (size_t)bIdx * CC * LL + (size_t)m * LL + l;
          xo[o] = resid[o] + acc[i][j][e] + bias[m];
        }
      }
  } else {
    #pragma unroll
    for (int i = 0; i < 4; i++)
      #pragma unroll
      for (int j = 0; j < 4; j++){
        int mm = m0 + wr * 64 + j * 16 + r15;
        float bv = bias[mm];
        #pragma unroll
        for (int e = 0; e < 4; e++){
          int n = n0 + wc * 64 + i * 16 + g * 4 + e;
          float t = acc[i][j][e] + bv;
          float gv = 0.5f * t * (1.0f + erff(t * 0.70710678118654752f));
          ho[(size_t)n * CC + mm] = f2bf(gv);
        }
      }
  }
}

// ---------------- per-(b,h,d) L2 norm over L for q and k ----------------
__global__ void rownorm_k(const bf16* __restrict__ q, const bf16* __restrict__ k,
                          float* __restrict__ qn, float* __restrict__ kn){
  __shared__ float red[256];
  int row = blockIdx.x;
  const bf16* src = (row < 2048) ? q : k;
  int r = (row < 2048) ? row : row - 2048;
  const bf16* p = src + (size_t)r * LL;
  float s = 0.f;
  for (int i = threadIdx.x; i < LL; i += 256){ float v = bf2f(p[i]); s += v * v; }
  red[threadIdx.x] = s; __syncthreads();
  for (int st = 128; st > 0; st >>= 1){ if (threadIdx.x < st) red[threadIdx.x] += red[threadIdx.x + st]; __syncthreads(); }
  if (threadIdx.x == 0){
    float nv = fmaxf(sqrtf(red[0]), 1e-12f);
    if (row < 2048) qn[r] = nv; else kn[r] = nv;
  }
}

__global__ void clsg_k(const float* __restrict__ cls_embs, const float* __restrict__ gamma_g,
                       const float* __restrict__ beta_g, const float* __restrict__ Wg,
                       float* __restrict__ g, bf16* __restrict__ gnb){
  __shared__ float cn[DD];
  __shared__ float red[256];
  __shared__ float gsh[CC];
  __shared__ float nrm[NHEAD];
  int n = blockIdx.x;
  const float* e = cls_embs + (size_t)n * DD;
  float s = 0.f, ss = 0.f;
  for (int i = threadIdx.x; i < DD; i += 256){ float v = e[i]; s += v; ss += v * v; }
  red[threadIdx.x] = s; __syncthreads();
  for (int st = 128; st > 0; st >>= 1){ if (threadIdx.x < st) red[threadIdx.x] += red[threadIdx.x + st]; __syncthreads(); }
  float mean = red[0] / DD; __syncthreads();
  red[threadIdx.x] = ss; __syncthreads();
  for (int st = 128; st > 0; st >>= 1){ if (threadIdx.x < st) red[threadIdx.x] += red[threadIdx.x + st]; __syncthreads(); }
  float var = red[0] / DD - mean * mean;
  float rstd = rsqrtf(var + EPSV);
  __syncthreads();
  for (int i = threadIdx.x; i < DD; i += 256) cn[i] = (e[i] - mean) * rstd * gamma_g[i] + beta_g[i];
  __syncthreads();
  for (int c = threadIdx.x; c < CC; c += 256){
    const float* w = Wg + (size_t)c * DD;
    float a = 0.f;
    #pragma unroll 8
    for (int d = 0; d < DD; d++) a += cn[d] * w[d];
    gsh[c] = a;
  }
  __syncthreads();
  if (threadIdx.x < NHEAD){
    float a = 0.f;
    for (int d = 0; d < HDIM; d++){ float v = gsh[threadIdx.x * HDIM + d]; a += v * v; }
    nrm[threadIdx.x] = fmaxf(sqrtf(a), 1e-12f);
  }
  __syncthreads();
  for (int c = threadIdx.x; c < CC; c += 256){
    g[(size_t)n * CC + c] = gsh[c];
    gnb[(size_t)n * CC + c] = f2bf(gsh[c] / nrm[c >> 6]);
  }
}

__global__ void clsobj_k(const float* __restrict__ g, const float* __restrict__ cls_l,
                         float* __restrict__ cls_obj){
  int idx = blockIdx.x * 256 + threadIdx.x;
  if (idx >= BB * CC) return;
  int b = idx >> 9, c = idx & 511;
  float a = 0.f;
  for (int n = 0; n < NCLS; n++) a += g[(size_t)n * CC + c] * cls_l[b * NCLS + n];
  cls_obj[idx] = a;
}

// ---------------- gm pass 1 (MFMA): per-(bh,n) min/max over l ----------------
__global__ __launch_bounds__(256) void gm1_k(const bf16* __restrict__ q, const bf16* __restrict__ gnb,
        float* __restrict__ pmin, float* __restrict__ pmax){
  __shared__ bf16 qs[64 * 68];
  __shared__ float sspart[4][64];
  __shared__ float rq[64];
  int bh = blockIdx.x, lt = blockIdx.y;
  int l0 = lt * 64;
  int t = threadIdx.x;
  int b = bh >> 3, h = bh & 7;
  int w = t >> 6, lane = t & 63, r15 = lane & 15, g = lane >> 4;
  const bf16* qp = q + (size_t)b * CC * LL + (size_t)h * HDIM * LL + l0;
  // stage q tile [d][l] -> qs[d][l] (pad 68)
  #pragma unroll
  for (int i2 = 0; i2 < 4; i2++){
    int idx = t + i2 * 256;
    int d = idx >> 4, lch = (idx & 15) * 4;
    short4v vv = *reinterpret_cast<const short4v*>(qp + (size_t)d * LL + lch);
    *(short4v*)&qs[d * 68 + lch] = vv;
  }
  __syncthreads();
  {
    int l = t & 63, dg = t >> 6;
    float ss = 0.f;
    #pragma unroll
    for (int dd = 0; dd < 16; dd++){ float v = bf2f(qs[(dg * 16 + dd) * 68 + l]); ss += v * v; }
    sspart[dg][l] = ss;
  }
  __syncthreads();
  if (t < 64){
    float ss = sspart[0][t] + sspart[1][t] + sspart[2][t] + sspart[3][t];
    rq[t] = 1.0f / fmaxf(sqrtf(ss), 1e-12f);
  }
  __syncthreads();
  // A frags: gn rows n = w*32 + i*16 + r15
  short8v ag[2][2];
  #pragma unroll
  for (int i = 0; i < 2; i++)
    #pragma unroll
    for (int kt = 0; kt < 2; kt++)
      ag[i][kt] = *reinterpret_cast<const short8v*>(gnb + (size_t)(w * 32 + i * 16 + r15) * CC + h * 64 + kt * 32 + g * 8);
  // B frags: qn[l][d] via transpose-read
  short8v bq[4][2];
  #pragma unroll
  for (int j = 0; j < 4; j++){
    float rqv = rq[j * 16 + r15];
    #pragma unroll
    for (int kt = 0; kt < 2; kt++){
      short8v bb;
      #pragma unroll
      for (int jj = 0; jj < 8; jj++){
        int d = kt * 32 + g * 8 + jj;
        bb[jj] = bfbits(bf2f(qs[d * 68 + j * 16 + r15]) * rqv);
      }
      bq[j][kt] = bb;
    }
  }
  f32x4 acc[2][4];
  #pragma unroll
  for (int i = 0; i < 2; i++)
    #pragma unroll
    for (int j = 0; j < 4; j++) acc[i][j] = (f32x4){0.f,0.f,0.f,0.f};
  #pragma unroll
  for (int kt = 0; kt < 2; kt++)
    #pragma unroll
    for (int i = 0; i < 2; i++)
      #pragma unroll
      for (int j = 0; j < 4; j++)
        acc[i][j] = __builtin_amdgcn_mfma_f32_16x16x32_bf16(ag[i][kt], bq[j][kt], acc[i][j], 0, 0, 0);
  // min/max over l (cols): in-lane over j, cross-lane over r15 bits
  #pragma unroll
  for (int i = 0; i < 2; i++)
    #pragma unroll
    for (int e = 0; e < 4; e++){
      float mn = acc[i][0][e], mx = acc[i][0][e];
      #pragma unroll
      for (int j = 1; j < 4; j++){ mn = fminf(mn, acc[i][j][e]); mx = fmaxf(mx, acc[i][j][e]); }
      #pragma unroll
      for (int msk = 1; msk < 16; msk <<= 1){
        mn = fminf(mn, __shfl_xor(mn, msk));
        mx = fmaxf(mx, __shfl_xor(mx, msk));
      }
      if (r15 == 0){
        int n = w * 32 + i * 16 + g * 4 + e;
        pmin[((size_t)bh * 128 + n) * GMBLK + lt] = mn;
        pmax[((size_t)bh * 128 + n) * GMBLK + lt] = mx;
      }
    }
}

__global__ void gmred_k(const float* __restrict__ pmin, const float* __restrict__ pmax,
                        float* __restrict__ gmin, float* __restrict__ gms){
  __shared__ float rmn[64], rmx[64];
  int row = blockIdx.x;
  float mn = 1e30f, mx = -1e30f;
  for (int i = threadIdx.x; i < GMBLK; i += 64){
    mn = fminf(mn, pmin[(size_t)row * GMBLK + i]);
    mx = fmaxf(mx, pmax[(size_t)row * GMBLK + i]);
  }
  rmn[threadIdx.x] = mn; rmx[threadIdx.x] = mx; __syncthreads();
  for (int st = 32; st > 0; st >>= 1){
    if (threadIdx.x < st){
      rmn[threadIdx.x] = fminf(rmn[threadIdx.x], rmn[threadIdx.x + st]);
      rmx[threadIdx.x] = fmaxf(rmx[threadIdx.x], rmx[threadIdx.x + st]);
    }
    __syncthreads();
  }
  if (threadIdx.x == 0){ gmin[row] = rmn[0]; gms[row] = rmx[0] - rmn[0]; }
}

__global__ void seg_k(const float* __restrict__ seg, const bf16* __restrict__ k, float* __restrict__ seg_num){
  __shared__ float red[256];
  int bc = blockIdx.x;
  int b = bc >> 9;
  const bf16* p = k + (size_t)bc * LL;
  const float* sp = seg + (size_t)b * LL;
  float s = 0.f;
  for (int i = threadIdx.x; i < LL; i += 256){
    float m = 1.0f / (1.0f + expf(-sp[i]));
    s += m * bf2f(p[i]);
  }
  red[threadIdx.x] = s; __syncthreads();
  for (int st = 128; st > 0; st >>= 1){ if (threadIdx.x < st) red[threadIdx.x] += red[threadIdx.x + st]; __syncthreads(); }
  if (threadIdx.x == 0) seg_num[bc] = red[0];
}

__global__ void segden_k(const float* __restrict__ seg, float* __restrict__ den){
  __shared__ float red[256];
  int b = blockIdx.x;
  const float* sp = seg + (size_t)b * LL;
  float s = 0.f;
  for (int i = threadIdx.x; i < LL; i += 256) s += 1.0f / (1.0f + expf(-sp[i]));
  red[threadIdx.x] = s; __syncthreads();
  for (int st = 128; st > 0; st >>= 1){ if (threadIdx.x < st) red[threadIdx.x] += red[threadIdx.x + st]; __syncthreads(); }
  if (threadIdx.x == 0) den[b] = red[0];
}

__global__ void obj_k(const float* __restrict__ cls_obj, const float* __restrict__ seg_num,
                      const float* __restrict__ den, float* __restrict__ obj){
  __shared__ float sval[2048];
  __shared__ float nrm[32];
  int tid = threadIdx.x;
  #pragma unroll
  for (int i = 0; i < 8; i++){
    int idx = tid + i * 256;
    int b = idx >> 9;
    sval[idx] = cls_obj[idx] + seg_num[idx] / den[b];
  }
  __syncthreads();
  if (tid < 32){
    float s = 0.f;
    for (int d = 0; d < 64; d++){ float v = sval[tid * 64 + d]; s += v * v; }
    nrm[tid] = fmaxf(sqrtf(s), 1e-12f);
  }
  __syncthreads();
  #pragma unroll
  for (int i = 0; i < 8; i++){
    int idx = tid + i * 256;
    obj[idx] = sval[idx] / nrm[idx >> 6];
  }
}

__global__ void aux_k(const bf16* __restrict__ k, const float* __restrict__ obj, float* __restrict__ aux,
                      float* __restrict__ pmin, float* __restrict__ pmax){
  __shared__ float os[64];
  __shared__ float rmn[256], rmx[256];
  int bh = blockIdx.x, lt = blockIdx.y;
  int b = bh >> 3, h = bh & 7;
  int l = lt * 256 + threadIdx.x;
  if (threadIdx.x < 64) os[threadIdx.x] = obj[bh * 64 + threadIdx.x];
  __syncthreads();
  const bf16* kp = k + (size_t)b * CC * LL + (size_t)h * HDIM * LL + l;
  float ss = 0.f, dot = 0.f;
  #pragma unroll 8
  for (int d = 0; d < 64; d++){ float v = bf2f(kp[(size_t)d * LL]); ss += v * v; dot += os[d] * v; }
  float av = dot / fmaxf(sqrtf(ss), 1e-12f);
  aux[(size_t)bh * LL + l] = av;
  rmn[threadIdx.x] = av; rmx[threadIdx.x] = av; __syncthreads();
  for (int st = 128; st > 0; st >>= 1){
    if (threadIdx.x < st){
      rmn[threadIdx.x] = fminf(rmn[threadIdx.x], rmn[threadIdx.x + st]);
      rmx[threadIdx.x] = fmaxf(rmx[threadIdx.x], rmx[threadIdx.x + st]);
    }
    __syncthreads();
  }
  if (threadIdx.x == 0){ pmin[bh * AUXBLK + lt] = rmn[0]; pmax[bh * AUXBLK + lt] = rmx[0]; }
}

__global__ void auxred_k(const float* __restrict__ pmin, const float* __restrict__ pmax,
                         float* __restrict__ amin, float* __restrict__ ams){
  __shared__ float rmn[64], rmx[64];
  int bh = blockIdx.x;
  float mn = 1e30f, mx = -1e30f;
  for (int i = threadIdx.x; i < AUXBLK; i += 64){
    mn = fminf(mn, pmin[bh * AUXBLK + i]);
    mx = fmaxf(mx, pmax[bh * AUXBLK + i]);
  }
  rmn[threadIdx.x] = mn; rmx[threadIdx.x] = mx; __syncthreads();
  for (int st = 32; st > 0; st >>= 1){
    if (threadIdx.x < st){
      rmn[threadIdx.x] = fminf(rmn[threadIdx.x], rmn[threadIdx.x + st]);
      rmx[threadIdx.x] = fmaxf(rmx[threadIdx.x], rmx[threadIdx.x + st]);
    }
    __syncthreads();
  }
  if (threadIdx.x == 0){ amin[bh] = rmn[0]; ams[bh] = rmx[0] - rmn[0]; }
}

// ---------------- channel attention (MFMA over l) ----------------
__global__ __launch_bounds__(256) void attn_k(const bf16* __restrict__ q, const bf16* __restrict__ k,
                                              float* __restrict__ part){
  __shared__ float red[4 * 4096];
  int ls = blockIdx.x, bh = blockIdx.y;
  int b = bh >> 3, h = bh & 7;
  int t = threadIdx.x;
  int w = t >> 6, lane = t & 63, r15 = lane & 15, g = lane >> 4;
  const bf16* qp = q + (size_t)b * CC * LL + (size_t)h * HDIM * LL;
  const bf16* kp = k + (size_t)b * CC * LL + (size_t)h * HDIM * LL;
  int kbase = ls * 1152 + w * 288;
  f32x4 acc[4][4];
  #pragma unroll
  for (int i = 0; i < 4; i++)
    #pragma unroll
    for (int j = 0; j < 4; j++) acc[i][j] = (f32x4){0.f,0.f,0.f,0.f};
  for (int ks = 0; ks < 9; ks++){
    int koff = kbase + ks * 32 + g * 8;
    short8v aq[4], bk[4];
    #pragma unroll
    for (int i = 0; i < 4; i++) aq[i] = *reinterpret_cast<const short8v*>(qp + (size_t)(i * 16 + r15) * LL + koff);
    #pragma unroll
    for (int j = 0; j < 4; j++) bk[j] = *reinterpret_cast<const short8v*>(kp + (size_t)(j * 16 + r15) * LL + koff);
    #pragma unroll
    for (int i = 0; i < 4; i++)
      #pragma unroll
      for (int j = 0; j < 4; j++)
        acc[i][j] = __builtin_amdgcn_mfma_f32_16x16x32_bf16(aq[i], bk[j], acc[i][j], 0, 0, 0);
  }
  #pragma unroll
  for (int i = 0; i < 4; i++)
    #pragma unroll
    for (int j = 0; j < 4; j++)
      #pragma unroll
      for (int e = 0; e < 4; e++)
        red[w * 4096 + (i * 16 + g * 4 + e) * 64 + j * 16 + r15] = acc[i][j][e];
  __syncthreads();
  #pragma unroll
  for (int it = 0; it < 16; it++){
    int idx = t + it * 256;
    part[((size_t)(bh * LSPLIT + ls)) * 4096 + idx] = red[idx] + red[4096 + idx] + red[8192 + idx] + red[12288 + idx];
  }
}

__global__ void smax_k(const float* __restrict__ part, const float* __restrict__ qn,
                       const float* __restrict__ kn, const float* __restrict__ scale,
                       bf16* __restrict__ Pb){
  __shared__ float As[64 * 65];
  int bh = blockIdx.x;
  int h = bh & 7;
  int tid = threadIdx.x;
  #pragma unroll
  for (int i = 0; i < 16; i++){
    int cell = tid + i * 256;
    int d = cell >> 6, e = cell & 63;
    float s = 0.f;
    #pragma unroll
    for (int ls = 0; ls < LSPLIT; ls++) s += part[((size_t)(bh * LSPLIT + ls)) * 4096 + cell];
    As[d * 65 + e] = s * scale[h] / (qn[bh * 64 + d] * kn[bh * 64 + e]);
  }
  __syncthreads();
  if (tid < 64){
    int d = tid;
    float mx = -1e30f;
    for (int e = 0; e < 64; e++) mx = fmaxf(mx, As[d * 65 + e]);
    float sum = 0.f;
    for (int e = 0; e < 64; e++){ float ev = expf(As[d * 65 + e] - mx); As[d * 65 + e] = ev; sum += ev; }
    float inv = 1.0f / sum;
    for (int e = 0; e < 64; e++) Pb[(size_t)bh * 4096 + d * 64 + e] = f2bf(As[d * 65 + e] * inv);
  }
}

// ---------------- pv (MFMA): gm recompute + softmax-combine + P@(v) * w[l] ----------------
__global__ __launch_bounds__(256) void pv_k(const bf16* __restrict__ q, const bf16* __restrict__ gnb,
      const float* __restrict__ aux,
      const float* __restrict__ gmin, const float* __restrict__ gms,
      const float* __restrict__ amin, const float* __restrict__ ams,
      const bf16* __restrict__ Pb, const bf16* __restrict__ vT, bf16* __restrict__ outT){
  __shared__ bf16 qs[64 * 68];
  __shared__ float sspart[4][64];
  __shared__ float rq[64];
  __shared__ float gminS[128], rgmsS[128];
  __shared__ float separt[4][64], setpart[4][64];
  __shared__ float wl[64];
  int bh = blockIdx.x, lt = blockIdx.y;
  int l0 = lt * 64;
  int t = threadIdx.x;
  int b = bh >> 3, h = bh & 7;
  int w = t >> 6, lane = t & 63, r15 = lane & 15, g = lane >> 4;
  if (t < 128){ gminS[t] = gmin[bh * 128 + t]; rgmsS[t] = 1.0f / gms[bh * 128 + t]; }
  const bf16* qp = q + (size_t)b * CC * LL + (size_t)h * HDIM * LL + l0;
  #pragma unroll
  for (int i2 = 0; i2 < 4; i2++){
    int idx = t + i2 * 256;
    int d = idx >> 4, lch = (idx & 15) * 4;
    short4v vv = *reinterpret_cast<const short4v*>(qp + (size_t)d * LL + lch);
    *(short4v*)&qs[d * 68 + lch] = vv;
  }
  __syncthreads();
  {
    int l = t & 63, dg = t >> 6;
    float ss = 0.f;
    #pragma unroll
    for (int dd = 0; dd < 16; dd++){ float v = bf2f(qs[(dg * 16 + dd) * 68 + l]); ss += v * v; }
    sspart[dg][l] = ss;
  }
  __syncthreads();
  if (t < 64){
    float ss = sspart[0][t] + sspart[1][t] + sspart[2][t] + sspart[3][t];
    rq[t] = 1.0f / fmaxf(sqrtf(ss), 1e-12f);
  }
  __syncthreads();
  // gm MFMA
  short8v ag[2][2];
  #pragma unroll
  for (int i = 0; i < 2; i++)
    #pragma unroll
    for (int kt = 0; kt < 2; kt++)
      ag[i][kt] = *reinterpret_cast<const short8v*>(gnb + (size_t)(w * 32 + i * 16 + r15) * CC + h * 64 + kt * 32 + g * 8);
  short8v bq[4][2];
  #pragma unroll
  for (int j = 0; j < 4; j++){
    float rqv = rq[j * 16 + r15];
    #pragma unroll
    for (int kt = 0; kt < 2; kt++){
      short8v bb;
      #pragma unroll
      for (int jj = 0; jj < 8; jj++){
        int d = kt * 32 + g * 8 + jj;
        bb[jj] = bfbits(bf2f(qs[d * 68 + j * 16 + r15]) * rqv);
      }
      bq[j][kt] = bb;
    }
  }
  f32x4 acc[2][4];
  #pragma unroll
  for (int i = 0; i < 2; i++)
    #pragma unroll
    for (int j = 0; j < 4; j++) acc[i][j] = (f32x4){0.f,0.f,0.f,0.f};
  #pragma unroll
  for (int kt = 0; kt < 2; kt++)
    #pragma unroll
    for (int i = 0; i < 2; i++)
      #pragma unroll
      for (int j = 0; j < 4; j++)
        acc[i][j] = __builtin_amdgcn_mfma_f32_16x16x32_bf16(ag[i][kt], bq[j][kt], acc[i][j], 0, 0, 0);
  // softmax-combine over n
  float seL[4] = {0.f,0.f,0.f,0.f}, setL[4] = {0.f,0.f,0.f,0.f};
  #pragma unroll
  for (int i = 0; i < 2; i++)
    #pragma unroll
    for (int j = 0; j < 4; j++)
      #pragma unroll
      for (int e = 0; e < 4; e++){
        int n = w * 32 + i * 16 + g * 4 + e;
        float tt = (acc[i][j][e] - gminS[n]) * rgmsS[n];
        float ee = __expf(tt);
        seL[j] += ee; setL[j] += ee * tt;
      }
  #pragma unroll
  for (int j = 0; j < 4; j++){
    seL[j] += __shfl_xor(seL[j], 16); seL[j] += __shfl_xor(seL[j], 32);
    setL[j] += __shfl_xor(setL[j], 16); setL[j] += __shfl_xor(setL[j], 32);
  }
  if (g == 0){
    #pragma unroll
    for (int j = 0; j < 4; j++){ separt[w][j * 16 + r15] = seL[j]; setpart[w][j * 16 + r15] = setL[j]; }
  }
  __syncthreads();
  if (t < 64){
    float se = separt[0][t] + separt[1][t] + separt[2][t] + separt[3][t];
    float st = setpart[0][t] + setpart[1][t] + setpart[2][t] + setpart[3][t];
    float gmred = st / se;
    float auxn = (aux[(size_t)bh * LL + l0 + t] - amin[bh]) / ams[bh];
    wl[t] = gmred * auxn;
  }
  __syncthreads();
  // PV MFMA: wave w covers cols l = w*16 + r15
  short8v ap[4][2];
  #pragma unroll
  for (int i = 0; i < 4; i++)
    #pragma unroll
    for (int kt = 0; kt < 2; kt++)
      ap[i][kt] = *reinterpret_cast<const short8v*>(Pb + (size_t)bh * 4096 + (i * 16 + r15) * 64 + kt * 32 + g * 8);
  const bf16* vrow = vT + ((size_t)b * LL + l0 + w * 16 + r15) * CC + h * 64;
  short8v bv[2];
  #pragma unroll
  for (int kt = 0; kt < 2; kt++) bv[kt] = *reinterpret_cast<const short8v*>(vrow + kt * 32 + g * 8);
  f32x4 oacc[4];
  #pragma unroll
  for (int i = 0; i < 4; i++) oacc[i] = (f32x4){0.f,0.f,0.f,0.f};
  #pragma unroll
  for (int kt = 0; kt < 2; kt++)
    #pragma unroll
    for (int i = 0; i < 4; i++)
      oacc[i] = __builtin_amdgcn_mfma_f32_16x16x32_bf16(ap[i][kt], bv[kt], oacc[i], 0, 0, 0);
  float wlv = wl[w * 16 + r15];
  bf16* orow = outT + ((size_t)b * LL + l0 + w * 16 + r15) * CC + h * 64;
  #pragma unroll
  for (int i = 0; i < 4; i++){
    short4v pk;
    #pragma unroll
    for (int e = 0; e < 4; e++) pk[e] = bfbits(oacc[i][e] * wlv);
    *(short4v*)&orow[i * 16 + g * 4] = pk;
  }
}

extern "C" void kernel_launch(void* const* d_in, const int* in_sizes, int n_in,
                              void* d_out, int out_size, void* d_ws, size_t ws_size,
                              hipStream_t stream){
  const float* img        = (const float*)d_in[0];
  const float* cls_embs   = (const float*)d_in[1];
  const float* cls_logits = (const float*)d_in[2];
  const float* seg        = (const float*)d_in[3];
  const float* gamma_g    = (const float*)d_in[4];
  const float* beta_g     = (const float*)d_in[5];
  const float* gamma_f    = (const float*)d_in[6];
  const float* beta_f     = (const float*)d_in[7];
  const float* attn_scale = (const float*)d_in[8];
  const float* Wg         = (const float*)d_in[9];
  const float* Wqkv       = (const float*)d_in[10];
  const float* Wo         = (const float*)d_in[11];
  const float* bo         = (const float*)d_in[12];
  const float* gamma_n    = (const float*)d_in[13];
  const float* beta_n     = (const float*)d_in[14];
  const float* W1         = (const float*)d_in[15];
  const float* b1         = (const float*)d_in[16];
  const float* W2         = (const float*)d_in[17];
  const float* b2         = (const float*)d_in[18];
  float* outp = (float*)d_out;
  (void)in_sizes; (void)n_in; (void)out_size;

  char* wsb = (char*)d_ws;
  size_t off = 0;
  auto alloc = [&](size_t bytes)->char*{
    char* p = wsb + off;
    off += (bytes + 255) & ~(size_t)255;
    return p;
  };
  float* mu1   = (float*)alloc((size_t)BLPIX * 4);
  float* rs1   = (float*)alloc((size_t)BLPIX * 4);
  float* qn    = (float*)alloc(2048 * 4);
  float* kn    = (float*)alloc(2048 * 4);
  float* gbuf  = (float*)alloc((size_t)NCLS * CC * 4);
  bf16*  gnbb  = (bf16*)alloc((size_t)NCLS * CC * 2);
  float* clsov = (float*)alloc(2048 * 4);
  float* segn  = (float*)alloc(2048 * 4);
  float* segd  = (float*)alloc(256);
  float* objv  = (float*)alloc(2048 * 4);
  float* gminp = (float*)alloc((size_t)32 * 128 * GMBLK * 4);
  float* gmaxp = (float*)alloc((size_t)32 * 128 * GMBLK * 4);
  float* gminv = (float*)alloc(4096 * 4);
  float* gmsv  = (float*)alloc(4096 * 4);
  float* auxv  = (float*)alloc((size_t)32 * LL * 4);
  float* apmin = (float*)alloc(32 * AUXBLK * 4);
  float* apmax = (float*)alloc(32 * AUXBLK * 4);
  float* aminv = (float*)alloc(256);
  float* amsv  = (float*)alloc(256);
  bf16*  Pb    = (bf16*)alloc((size_t)32 * 4096 * 2);
  float* apart = (float*)alloc((size_t)32 * LSPLIT * 4096 * 4);
  bf16* qb    = (bf16*)alloc((size_t)BB * CC * LL * 2);
  bf16* kb    = (bf16*)alloc((size_t)BB * CC * LL * 2);
  bf16* wqkvb = (bf16*)alloc((size_t)1536 * 512 * 2);
  bf16* wob   = (bf16*)alloc((size_t)512 * 512 * 2);
  bf16* w1b   = (bf16*)alloc((size_t)512 * 512 * 2);
  bf16* w2b   = (bf16*)alloc((size_t)512 * 512 * 2);
  // d_out partitioning (bf16 halves), lifetimes end before Wo-GEMM writes x:
  bf16* vT  = (bf16*)d_out;                                       // v [pixel][c]
  bf16* xnT = (bf16*)((char*)d_out + (size_t)BB * CC * LL * 2);   // LN(img)^T [pixel][c]
  // ws aliases (disjoint lifetimes):
  bf16* outT = kb;   // attention output [pixel][c] (k dead after attn/aux/seg)
  bf16* xnT2 = qb;   // LN(x)^T (q dead after pv_k)
  bf16* hbT  = kb;   // MLP hidden [pixel][c] (outT dead after Wo-GEMM)
  float* xb  = outp; // x fp32 in d_out from Wo-GEMM onward
  if (off > ws_size) return;

  ln_stats_k<<<BLPIX / 256, 256, 0, stream>>>(img, mu1, rs1);
  wcast_k<<<1536, 256, 0, stream>>>(Wqkv, Wo, W1, W2, wqkvb, wob, w1b, w2b);
  lnT_k<<<dim3(8, 576), 256, 0, stream>>>(img, mu1, rs1, gamma_f, beta_f, xnT);
  mgemm_k<0><<<dim3(12, 288), 256, 0, stream>>>(wqkvb, xnT, nullptr, nullptr,
      qb, kb, vT, nullptr, nullptr);
  rownorm_k<<<4096, 256, 0, stream>>>(qb, kb, qn, kn);
  clsg_k<<<NCLS, 256, 0, stream>>>(cls_embs, gamma_g, beta_g, Wg, gbuf, gnbb);
  clsobj_k<<<8, 256, 0, stream>>>(gbuf, cls_logits, clsov);
  gm1_k<<<dim3(32, GMBLK), 256, 0, stream>>>(qb, gnbb, gminp, gmaxp);
  gmred_k<<<4096, 64, 0, stream>>>(gminp, gmaxp, gminv, gmsv);
  seg_k<<<2048, 256, 0, stream>>>(seg, kb, segn);
  segden_k<<<BB, 256, 0, stream>>>(seg, segd);
  obj_k<<<1, 256, 0, stream>>>(clsov, segn, segd, objv);
  aux_k<<<dim3(32, AUXBLK), 256, 0, stream>>>(kb, objv, auxv, apmin, apmax);
  auxred_k<<<32, 64, 0, stream>>>(apmin, apmax, aminv, amsv);
  attn_k<<<dim3(LSPLIT, 32), 256, 0, stream>>>(qb, kb, apart);
  smax_k<<<32, 256, 0, stream>>>(apart, qn, kn, attn_scale, Pb);
  pv_k<<<dim3(32, GMBLK), 256, 0, stream>>>(qb, gnbb, auxv, gminv, gmsv, aminv, amsv, Pb, vT, outT);
  mgemm_k<1><<<dim3(4, 288), 256, 0, stream>>>(wob, outT, img, bo,
      nullptr, nullptr, nullptr, xb, nullptr);
  ln_stats_k<<<BLPIX / 256, 256, 0, stream>>>(xb, mu1, rs1);
  lnT_k<<<dim3(8, 576), 256, 0, stream>>>(xb, mu1, rs1, gamma_n, beta_n, xnT2);
  mgemm_k<2><<<dim3(4, 288), 256, 0, stream>>>(w1b, xnT2, nullptr, b1,
      nullptr, nullptr, nullptr, nullptr, hbT);
  mgemm_k<3><<<dim3(4, 288), 256, 0, stream>>>(w2b, hbT, xb, b2,
      nullptr, nullptr, nullptr, outp, nullptr);
}

// Round 5
// 497.643 us; speedup vs baseline: 4.5194x; 1.0860x over previous
//
#include <hip/hip_runtime.h>
#include <hip/hip_bf16.h>
#include <math.h>

#define BB 4
#define CC 512
#define NHEAD 8
#define HDIM 64
#define NCLS 128
#define DD 768
#define LL 9216
#define BLPIX 36864
#define EPSV 1e-5f
#define GMBLK 144
#define AUXBLK 36
#define LSPLIT 8

typedef __hip_bfloat16 bf16;
typedef __attribute__((ext_vector_type(8))) short short8v;
typedef __attribute__((ext_vector_type(4))) short short4v;
typedef __attribute__((ext_vector_type(4))) float f32x4;

__device__ __forceinline__ float bf2f(bf16 v){ return __bfloat162float(v); }
__device__ __forceinline__ bf16 f2bf(float v){ return __float2bfloat16(v); }
__device__ __forceinline__ short bfbits(float v){ bf16 b = __float2bfloat16(v); return *reinterpret_cast<short*>(&b); }
__device__ __forceinline__ float s2f(short s){ bf16 b = *reinterpret_cast<bf16*>(&s); return __bfloat162float(b); }

// ---------------- per-pixel LN stats over C (img) ----------------
__global__ void ln_stats_k(const float* __restrict__ X, float* __restrict__ mu, float* __restrict__ rs){
  int idx = blockIdx.x * blockDim.x + threadIdx.x;
  if (idx >= BLPIX) return;
  int b = idx / LL, l = idx % LL;
  const float* p = X + (size_t)b * CC * LL + l;
  float s = 0.f, ss = 0.f;
  #pragma unroll 8
  for (int c = 0; c < CC; c++){ float v = p[(size_t)c * LL]; s += v; ss += v * v; }
  float m = s * (1.0f / CC);
  float var = ss * (1.0f / CC) - m * m;
  mu[idx] = m; rs[idx] = rsqrtf(var + EPSV);
}

// ---------------- LN-apply + transpose: [b][c][l] fp32 -> [pixel][c] bf16 ----------------
__global__ __launch_bounds__(256) void lnT_k(const float* __restrict__ X,
    const float* __restrict__ mu, const float* __restrict__ rs,
    const float* __restrict__ lng, const float* __restrict__ lnb,
    bf16* __restrict__ out){
  __shared__ float t[64][65];
  int c0 = blockIdx.x * 64;
  int p0 = blockIdx.y * 64;
  int b = p0 / LL;
  int l0 = p0 - b * LL;
  int tid = threadIdx.x;
  #pragma unroll
  for (int i = 0; i < 16; i++){
    int idx = i * 256 + tid;
    int cl = idx >> 6, ll2 = idx & 63;
    t[cl][ll2] = X[(size_t)b * CC * LL + (size_t)(c0 + cl) * LL + l0 + ll2];
  }
  __syncthreads();
  int pr = tid >> 4;
  int cc = (tid & 15) * 4;
  #pragma unroll
  for (int i = 0; i < 4; i++){
    int pl = pr + i * 16;
    int p = p0 + pl;
    float m = mu[p], r = rs[p];
    short4v pk;
    #pragma unroll
    for (int e = 0; e < 4; e++){
      int c = c0 + cc + e;
      float v = (t[cc + e][pl] - m) * r * lng[c] + lnb[c];
      pk[e] = bfbits(v);
    }
    *(short4v*)&out[(size_t)p * CC + c0 + cc] = pk;
  }
}

// ---------------- weights fp32 -> bf16 ----------------
__global__ void wcast_k(const float* __restrict__ wqkv, const float* __restrict__ wo,
                        const float* __restrict__ w1, const float* __restrict__ w2,
                        bf16* __restrict__ oq, bf16* __restrict__ oo,
                        bf16* __restrict__ o1, bf16* __restrict__ o2){
  int i = blockIdx.x * 256 + threadIdx.x;
  int e = i * 4;
  const float* src; bf16* dst; int off;
  if (e < 786432){ src = wqkv; dst = oq; off = e; }
  else if (e < 1048576){ src = wo; dst = oo; off = e - 786432; }
  else if (e < 1310720){ src = w1; dst = o1; off = e - 1048576; }
  else { src = w2; dst = o2; off = e - 1310720; }
  float4 v = *reinterpret_cast<const float4*>(src + off);
  short4v pk;
  pk[0] = bfbits(v.x); pk[1] = bfbits(v.y); pk[2] = bfbits(v.z); pk[3] = bfbits(v.w);
  *(short4v*)&dst[off] = pk;
}

// ---------------- stats reduce: statp[4][BLPIX] -> mu, rs ----------------
__global__ void statsred_k(const float2* __restrict__ statp, float* __restrict__ mu, float* __restrict__ rs){
  int p = blockIdx.x * 256 + threadIdx.x;
  if (p >= BLPIX) return;
  float s = 0.f, ss = 0.f;
  #pragma unroll
  for (int part = 0; part < 4; part++){
    float2 v = statp[part * BLPIX + p];
    s += v.x; ss += v.y;
  }
  float m = s * (1.0f / CC);
  float var = ss * (1.0f / CC) - m * m;
  mu[p] = m; rs[p] = rsqrtf(var + EPSV);
}

// ---------------- bf16 MFMA GEMM: C[M][N] = A[M][512] @ B[N][512]^T ----------------
// MODE 0: q/k [b][c][l] bf16, v -> vT [pixel][c] bf16
// MODE 1: xT = bf16(img + C + bo) [pixel][c] + fused LN stats partials
// MODE 2: h = gelu(C+b1) bf16 [pixel][c], B = xT with inline LN
// MODE 3: d_out = xT + C + b2 (fp32 [b][c][l])
template<int MODE>
__global__ __launch_bounds__(256, 2) void mgemm_k(
    const bf16* __restrict__ A,
    const bf16* __restrict__ B,
    const float* __restrict__ residf,   // MODE1: img
    const bf16*  __restrict__ residb,   // MODE3: xT
    const float* __restrict__ bias,
    const float* __restrict__ mu, const float* __restrict__ rs,
    const float* __restrict__ lng, const float* __restrict__ lnb,  // MODE2 LN
    float2* __restrict__ statp,         // MODE1 stats partials
    bf16* __restrict__ qo, bf16* __restrict__ ko, bf16* __restrict__ vo,
    bf16* __restrict__ xT_out,
    float* __restrict__ xo,
    bf16* __restrict__ ho)
{
  __shared__ short Asm[128 * 64];
  __shared__ short Bsm[128 * 64];
  __shared__ float sred[4][4][16][2];
  int tid = threadIdx.x;
  int lane = tid & 63, wv = tid >> 6;
  int wr = wv >> 1, wc = wv & 1;
  int r15 = lane & 15, g = lane >> 4, h7 = lane & 7;
  // XCD-aware bijective swizzle (nwg % 8 == 0 for all our grids)
  int gx = gridDim.x;
  int flat = blockIdx.y * gx + blockIdx.x;
  int cpx = (gx * gridDim.y) >> 3;
  int swz = (flat & 7) * cpx + (flat >> 3);
  int m0 = (swz % gx) * 128, n0 = (swz / gx) * 128;
  int srow = tid >> 3, skkg = tid & 7;
  int sslot = ((skkg ^ (srow & 7))) * 8;

  f32x4 acc[4][4];
  #pragma unroll
  for (int i = 0; i < 4; i++)
    #pragma unroll
    for (int j = 0; j < 4; j++) acc[i][j] = (f32x4){0.f, 0.f, 0.f, 0.f};

  short8v pa[4], pb[4];
  auto loadAB = [&](int it){
    int k0 = it * 64;
    if (MODE == 2){
      int c0 = k0 + skkg * 8;
      float ga[8], be[8];
      *(float4*)&ga[0] = *(const float4*)&lng[c0];
      *(float4*)&ga[4] = *(const float4*)&lng[c0 + 4];
      *(float4*)&be[0] = *(const float4*)&lnb[c0];
      *(float4*)&be[4] = *(const float4*)&lnb[c0 + 4];
      #pragma unroll
      for (int r = 0; r < 4; r++){
        pa[r] = *reinterpret_cast<const short8v*>(A + (size_t)(m0 + r * 32 + srow) * 512 + c0);
        int rp = n0 + r * 32 + srow;
        float mm = mu[rp], rr = rs[rp];
        short8v raw = *reinterpret_cast<const short8v*>(B + (size_t)rp * 512 + c0);
        short8v ov;
        #pragma unroll
        for (int e = 0; e < 8; e++){
          float v = (s2f(raw[e]) - mm) * rr * ga[e] + be[e];
          ov[e] = bfbits(v);
        }
        pb[r] = ov;
      }
    } else {
      #pragma unroll
      for (int r = 0; r < 4; r++){
        pa[r] = *reinterpret_cast<const short8v*>(A + (size_t)(m0 + r * 32 + srow) * 512 + k0 + skkg * 8);
        pb[r] = *reinterpret_cast<const short8v*>(B + (size_t)(n0 + r * 32 + srow) * 512 + k0 + skkg * 8);
      }
    }
  };

  loadAB(0);
  for (int it = 0; it < 8; ++it){
    __syncthreads();
    #pragma unroll
    for (int r = 0; r < 4; r++){
      int row = r * 32 + srow;
      *(short8v*)&Asm[row * 64 + sslot] = pa[r];
      *(short8v*)&Bsm[row * 64 + sslot] = pb[r];
    }
    __syncthreads();
    if (it < 7) loadAB(it + 1);
    #pragma unroll
    for (int s = 0; s < 2; s++){
      int slot = ((s * 4 + g) ^ h7) * 8;
      short8v af[4], bf_[4];
      #pragma unroll
      for (int i = 0; i < 4; i++){
        af[i]  = *(const short8v*)&Asm[(wr * 64 + i * 16 + r15) * 64 + slot];
        bf_[i] = *(const short8v*)&Bsm[(wc * 64 + i * 16 + r15) * 64 + slot];
      }
      #pragma unroll
      for (int i = 0; i < 4; i++)
        #pragma unroll
        for (int j = 0; j < 4; j++){
          if (MODE == 2)
            acc[i][j] = __builtin_amdgcn_mfma_f32_16x16x32_bf16(bf_[i], af[j], acc[i][j], 0, 0, 0);
          else
            acc[i][j] = __builtin_amdgcn_mfma_f32_16x16x32_bf16(af[i], bf_[j], acc[i][j], 0, 0, 0);
        }
    }
  }

  int bIdx = n0 / LL;
  int lbase = n0 - bIdx * LL;
  if (MODE == 0){
    int part = m0 >> 9;
    if (part < 2){
      bf16* dst = (part == 0) ? qo : ko;
      int chb = (m0 & 511) + wr * 64;
      #pragma unroll
      for (int i = 0; i < 4; i++)
        #pragma unroll
        for (int j = 0; j < 4; j++){
          int l = lbase + wc * 64 + j * 16 + r15;
          #pragma unroll
          for (int e = 0; e < 4; e++){
            int ch = chb + i * 16 + g * 4 + e;
            dst[(size_t)bIdx * CC * LL + (size_t)ch * LL + l] = f2bf(acc[i][j][e]);
          }
        }
    } else {
      int chb = (m0 & 511) + wr * 64;
      #pragma unroll
      for (int i = 0; i < 4; i++)
        #pragma unroll
        for (int j = 0; j < 4; j++){
          int l = lbase + wc * 64 + j * 16 + r15;
          int ch = chb + i * 16 + g * 4;
          short4v pk;
          #pragma unroll
          for (int e = 0; e < 4; e++) pk[e] = bfbits(acc[i][j][e]);
          *(short4v*)&vo[((size_t)bIdx * LL + l) * CC + ch] = pk;
        }
    }
  } else if (MODE == 1){
    float sj[4] = {0.f,0.f,0.f,0.f}, ssj[4] = {0.f,0.f,0.f,0.f};
    #pragma unroll
    for (int i = 0; i < 4; i++)
      #pragma unroll
      for (int j = 0; j < 4; j++){
        int l = lbase + wc * 64 + j * 16 + r15;
        int chm = m0 + wr * 64 + i * 16 + g * 4;
        short4v pk;
        #pragma unroll
        for (int e = 0; e < 4; e++){
          int m = chm + e;
          size_t o = (size_t)bIdx * CC * LL + (size_t)m * LL + l;
          float xv = residf[o] + acc[i][j][e] + bias[m];
          pk[e] = bfbits(xv);
          sj[j] += xv; ssj[j] += xv * xv;
        }
        *(short4v*)&xT_out[((size_t)bIdx * LL + l) * CC + chm] = pk;
      }
    #pragma unroll
    for (int j = 0; j < 4; j++){
      sj[j] += __shfl_xor(sj[j], 16); sj[j] += __shfl_xor(sj[j], 32);
      ssj[j] += __shfl_xor(ssj[j], 16); ssj[j] += __shfl_xor(ssj[j], 32);
    }
    if (g == 0){
      #pragma unroll
      for (int j = 0; j < 4; j++){ sred[wv][j][r15][0] = sj[j]; sred[wv][j][r15][1] = ssj[j]; }
    }
    __syncthreads();
    if (tid < 128){
      int wv2 = tid >> 6, lane2 = tid & 63, j2 = lane2 >> 4, r2 = lane2 & 15;
      float s = sred[wv2][j2][r2][0] + sred[wv2 + 2][j2][r2][0];
      float ss2 = sred[wv2][j2][r2][1] + sred[wv2 + 2][j2][r2][1];
      int p = n0 + wv2 * 64 + j2 * 16 + r2;
      statp[(m0 >> 7) * BLPIX + p] = make_float2(s, ss2);
    }
  } else if (MODE == 3){
    #pragma unroll
    for (int i = 0; i < 4; i++)
      #pragma unroll
      for (int j = 0; j < 4; j++){
        int l = lbase + wc * 64 + j * 16 + r15;
        int chm = m0 + wr * 64 + i * 16 + g * 4;
        short4v rv = *(const short4v*)&residb[((size_t)bIdx * LL + l) * CC + chm];
        #pragma unroll
        for (int e = 0; e < 4; e++){
          int m = chm + e;
          size_t o = (size_t)bIdx * CC * LL + (size_t)m * LL + l;
          xo[o] = s2f(rv[e]) + acc[i][j][e] + bias[m];
        }
      }
  } else {
    #pragma unroll
    for (int i = 0; i < 4; i++)
      #pragma unroll
      for (int j = 0; j < 4; j++){
        int mm = m0 + wr * 64 + j * 16 + r15;
        float bv = bias[mm];
        #pragma unroll
        for (int e = 0; e < 4; e++){
          int n = n0 + wc * 64 + i * 16 + g * 4 + e;
          float t = acc[i][j][e] + bv;
          float gv = 0.5f * t * (1.0f + erff(t * 0.70710678118654752f));
          ho[(size_t)n * CC + mm] = f2bf(gv);
        }
      }
  }
}

// ---------------- per-(b,h,d) L2 norm over L for q and k ----------------
__global__ void rownorm_k(const bf16* __restrict__ q, const bf16* __restrict__ k,
                          float* __restrict__ qn, float* __restrict__ kn){
  __shared__ float red[256];
  int row = blockIdx.x;
  const bf16* src = (row < 2048) ? q : k;
  int r = (row < 2048) ? row : row - 2048;
  const bf16* p = src + (size_t)r * LL;
  float s = 0.f;
  for (int i = threadIdx.x; i < LL; i += 256){ float v = bf2f(p[i]); s += v * v; }
  red[threadIdx.x] = s; __syncthreads();
  for (int st = 128; st > 0; st >>= 1){ if (threadIdx.x < st) red[threadIdx.x] += red[threadIdx.x + st]; __syncthreads(); }
  if (threadIdx.x == 0){
    float nv = fmaxf(sqrtf(red[0]), 1e-12f);
    if (row < 2048) qn[r] = nv; else kn[r] = nv;
  }
}

__global__ void clsg_k(const float* __restrict__ cls_embs, const float* __restrict__ gamma_g,
                       const float* __restrict__ beta_g, const float* __restrict__ Wg,
                       float* __restrict__ g, bf16* __restrict__ gnb){
  __shared__ float cn[DD];
  __shared__ float red[256];
  __shared__ float gsh[CC];
  __shared__ float nrm[NHEAD];
  int n = blockIdx.x;
  const float* e = cls_embs + (size_t)n * DD;
  float s = 0.f, ss = 0.f;
  for (int i = threadIdx.x; i < DD; i += 256){ float v = e[i]; s += v; ss += v * v; }
  red[threadIdx.x] = s; __syncthreads();
  for (int st = 128; st > 0; st >>= 1){ if (threadIdx.x < st) red[threadIdx.x] += red[threadIdx.x + st]; __syncthreads(); }
  float mean = red[0] / DD; __syncthreads();
  red[threadIdx.x] = ss; __syncthreads();
  for (int st = 128; st > 0; st >>= 1){ if (threadIdx.x < st) red[threadIdx.x] += red[threadIdx.x + st]; __syncthreads(); }
  float var = red[0] / DD - mean * mean;
  float rstd = rsqrtf(var + EPSV);
  __syncthreads();
  for (int i = threadIdx.x; i < DD; i += 256) cn[i] = (e[i] - mean) * rstd * gamma_g[i] + beta_g[i];
  __syncthreads();
  for (int c = threadIdx.x; c < CC; c += 256){
    const float* w = Wg + (size_t)c * DD;
    float a = 0.f;
    #pragma unroll 8
    for (int d = 0; d < DD; d++) a += cn[d] * w[d];
    gsh[c] = a;
  }
  __syncthreads();
  if (threadIdx.x < NHEAD){
    float a = 0.f;
    for (int d = 0; d < HDIM; d++){ float v = gsh[threadIdx.x * HDIM + d]; a += v * v; }
    nrm[threadIdx.x] = fmaxf(sqrtf(a), 1e-12f);
  }
  __syncthreads();
  for (int c = threadIdx.x; c < CC; c += 256){
    g[(size_t)n * CC + c] = gsh[c];
    gnb[(size_t)n * CC + c] = f2bf(gsh[c] / nrm[c >> 6]);
  }
}

__global__ void clsobj_k(const float* __restrict__ g, const float* __restrict__ cls_l,
                         float* __restrict__ cls_obj){
  int idx = blockIdx.x * 256 + threadIdx.x;
  if (idx >= BB * CC) return;
  int b = idx >> 9, c = idx & 511;
  float a = 0.f;
  for (int n = 0; n < NCLS; n++) a += g[(size_t)n * CC + c] * cls_l[b * NCLS + n];
  cls_obj[idx] = a;
}

// ---------------- gm pass 1 (MFMA): per-(bh,n) min/max over l ----------------
__global__ __launch_bounds__(256) void gm1_k(const bf16* __restrict__ q, const bf16* __restrict__ gnb,
        float* __restrict__ pmin, float* __restrict__ pmax){
  __shared__ bf16 qs[64 * 68];
  __shared__ float sspart[4][64];
  __shared__ float rq[64];
  int bh = blockIdx.x, lt = blockIdx.y;
  int l0 = lt * 64;
  int t = threadIdx.x;
  int b = bh >> 3, h = bh & 7;
  int w = t >> 6, lane = t & 63, r15 = lane & 15, g = lane >> 4;
  const bf16* qp = q + (size_t)b * CC * LL + (size_t)h * HDIM * LL + l0;
  #pragma unroll
  for (int i2 = 0; i2 < 4; i2++){
    int idx = t + i2 * 256;
    int d = idx >> 4, lch = (idx & 15) * 4;
    short4v vv = *reinterpret_cast<const short4v*>(qp + (size_t)d * LL + lch);
    *(short4v*)&qs[d * 68 + lch] = vv;
  }
  __syncthreads();
  {
    int l = t & 63, dg = t >> 6;
    float ss = 0.f;
    #pragma unroll
    for (int dd = 0; dd < 16; dd++){ float v = bf2f(qs[(dg * 16 + dd) * 68 + l]); ss += v * v; }
    sspart[dg][l] = ss;
  }
  __syncthreads();
  if (t < 64){
    float ss = sspart[0][t] + sspart[1][t] + sspart[2][t] + sspart[3][t];
    rq[t] = 1.0f / fmaxf(sqrtf(ss), 1e-12f);
  }
  __syncthreads();
  short8v ag[2][2];
  #pragma unroll
  for (int i = 0; i < 2; i++)
    #pragma unroll
    for (int kt = 0; kt < 2; kt++)
      ag[i][kt] = *reinterpret_cast<const short8v*>(gnb + (size_t)(w * 32 + i * 16 + r15) * CC + h * 64 + kt * 32 + g * 8);
  short8v bq[4][2];
  #pragma unroll
  for (int j = 0; j < 4; j++){
    float rqv = rq[j * 16 + r15];
    #pragma unroll
    for (int kt = 0; kt < 2; kt++){
      short8v bb;
      #pragma unroll
      for (int jj = 0; jj < 8; jj++){
        int d = kt * 32 + g * 8 + jj;
        bb[jj] = bfbits(bf2f(qs[d * 68 + j * 16 + r15]) * rqv);
      }
      bq[j][kt] = bb;
    }
  }
  f32x4 acc[2][4];
  #pragma unroll
  for (int i = 0; i < 2; i++)
    #pragma unroll
    for (int j = 0; j < 4; j++) acc[i][j] = (f32x4){0.f,0.f,0.f,0.f};
  #pragma unroll
  for (int kt = 0; kt < 2; kt++)
    #pragma unroll
    for (int i = 0; i < 2; i++)
      #pragma unroll
      for (int j = 0; j < 4; j++)
        acc[i][j] = __builtin_amdgcn_mfma_f32_16x16x32_bf16(ag[i][kt], bq[j][kt], acc[i][j], 0, 0, 0);
  #pragma unroll
  for (int i = 0; i < 2; i++)
    #pragma unroll
    for (int e = 0; e < 4; e++){
      float mn = acc[i][0][e], mx = acc[i][0][e];
      #pragma unroll
      for (int j = 1; j < 4; j++){ mn = fminf(mn, acc[i][j][e]); mx = fmaxf(mx, acc[i][j][e]); }
      #pragma unroll
      for (int msk = 1; msk < 16; msk <<= 1){
        mn = fminf(mn, __shfl_xor(mn, msk));
        mx = fmaxf(mx, __shfl_xor(mx, msk));
      }
      if (r15 == 0){
        int n = w * 32 + i * 16 + g * 4 + e;
        pmin[((size_t)bh * 128 + n) * GMBLK + lt] = mn;
        pmax[((size_t)bh * 128 + n) * GMBLK + lt] = mx;
      }
    }
}

__global__ void gmred_k(const float* __restrict__ pmin, const float* __restrict__ pmax,
                        float* __restrict__ gmin, float* __restrict__ gms){
  __shared__ float rmn[64], rmx[64];
  int row = blockIdx.x;
  float mn = 1e30f, mx = -1e30f;
  for (int i = threadIdx.x; i < GMBLK; i += 64){
    mn = fminf(mn, pmin[(size_t)row * GMBLK + i]);
    mx = fmaxf(mx, pmax[(size_t)row * GMBLK + i]);
  }
  rmn[threadIdx.x] = mn; rmx[threadIdx.x] = mx; __syncthreads();
  for (int st = 32; st > 0; st >>= 1){
    if (threadIdx.x < st){
      rmn[threadIdx.x] = fminf(rmn[threadIdx.x], rmn[threadIdx.x + st]);
      rmx[threadIdx.x] = fmaxf(rmx[threadIdx.x], rmx[threadIdx.x + st]);
    }
    __syncthreads();
  }
  if (threadIdx.x == 0){ gmin[row] = rmn[0]; gms[row] = rmx[0] - rmn[0]; }
}

__global__ void seg_k(const float* __restrict__ seg, const bf16* __restrict__ k, float* __restrict__ seg_num){
  __shared__ float red[256];
  int bc = blockIdx.x;
  int b = bc >> 9;
  const bf16* p = k + (size_t)bc * LL;
  const float* sp = seg + (size_t)b * LL;
  float s = 0.f;
  for (int i = threadIdx.x; i < LL; i += 256){
    float m = 1.0f / (1.0f + expf(-sp[i]));
    s += m * bf2f(p[i]);
  }
  red[threadIdx.x] = s; __syncthreads();
  for (int st = 128; st > 0; st >>= 1){ if (threadIdx.x < st) red[threadIdx.x] += red[threadIdx.x + st]; __syncthreads(); }
  if (threadIdx.x == 0) seg_num[bc] = red[0];
}

__global__ void segden_k(const float* __restrict__ seg, float* __restrict__ den){
  __shared__ float red[256];
  int b = blockIdx.x;
  const float* sp = seg + (size_t)b * LL;
  float s = 0.f;
  for (int i = threadIdx.x; i < LL; i += 256) s += 1.0f / (1.0f + expf(-sp[i]));
  red[threadIdx.x] = s; __syncthreads();
  for (int st = 128; st > 0; st >>= 1){ if (threadIdx.x < st) red[threadIdx.x] += red[threadIdx.x + st]; __syncthreads(); }
  if (threadIdx.x == 0) den[b] = red[0];
}

__global__ void obj_k(const float* __restrict__ cls_obj, const float* __restrict__ seg_num,
                      const float* __restrict__ den, float* __restrict__ obj){
  __shared__ float sval[2048];
  __shared__ float nrm[32];
  int tid = threadIdx.x;
  #pragma unroll
  for (int i = 0; i < 8; i++){
    int idx = tid + i * 256;
    int b = idx >> 9;
    sval[idx] = cls_obj[idx] + seg_num[idx] / den[b];
  }
  __syncthreads();
  if (tid < 32){
    float s = 0.f;
    for (int d = 0; d < 64; d++){ float v = sval[tid * 64 + d]; s += v * v; }
    nrm[tid] = fmaxf(sqrtf(s), 1e-12f);
  }
  __syncthreads();
  #pragma unroll
  for (int i = 0; i < 8; i++){
    int idx = tid + i * 256;
    obj[idx] = sval[idx] / nrm[idx >> 6];
  }
}

__global__ void aux_k(const bf16* __restrict__ k, const float* __restrict__ obj, float* __restrict__ aux,
                      float* __restrict__ pmin, float* __restrict__ pmax){
  __shared__ float os[64];
  __shared__ float rmn[256], rmx[256];
  int bh = blockIdx.x, lt = blockIdx.y;
  int b = bh >> 3, h = bh & 7;
  int l = lt * 256 + threadIdx.x;
  if (threadIdx.x < 64) os[threadIdx.x] = obj[bh * 64 + threadIdx.x];
  __syncthreads();
  const bf16* kp = k + (size_t)b * CC * LL + (size_t)h * HDIM * LL + l;
  float ss = 0.f, dot = 0.f;
  #pragma unroll 8
  for (int d = 0; d < 64; d++){ float v = bf2f(kp[(size_t)d * LL]); ss += v * v; dot += os[d] * v; }
  float av = dot / fmaxf(sqrtf(ss), 1e-12f);
  aux[(size_t)bh * LL + l] = av;
  rmn[threadIdx.x] = av; rmx[threadIdx.x] = av; __syncthreads();
  for (int st = 128; st > 0; st >>= 1){
    if (threadIdx.x < st){
      rmn[threadIdx.x] = fminf(rmn[threadIdx.x], rmn[threadIdx.x + st]);
      rmx[threadIdx.x] = fmaxf(rmx[threadIdx.x], rmx[threadIdx.x + st]);
    }
    __syncthreads();
  }
  if (threadIdx.x == 0){ pmin[bh * AUXBLK + lt] = rmn[0]; pmax[bh * AUXBLK + lt] = rmx[0]; }
}

__global__ void auxred_k(const float* __restrict__ pmin, const float* __restrict__ pmax,
                         float* __restrict__ amin, float* __restrict__ ams){
  __shared__ float rmn[64], rmx[64];
  int bh = blockIdx.x;
  float mn = 1e30f, mx = -1e30f;
  for (int i = threadIdx.x; i < AUXBLK; i += 64){
    mn = fminf(mn, pmin[bh * AUXBLK + i]);
    mx = fmaxf(mx, pmax[bh * AUXBLK + i]);
  }
  rmn[threadIdx.x] = mn; rmx[threadIdx.x] = mx; __syncthreads();
  for (int st = 32; st > 0; st >>= 1){
    if (threadIdx.x < st){
      rmn[threadIdx.x] = fminf(rmn[threadIdx.x], rmn[threadIdx.x + st]);
      rmx[threadIdx.x] = fmaxf(rmx[threadIdx.x], rmx[threadIdx.x + st]);
    }
    __syncthreads();
  }
  if (threadIdx.x == 0){ amin[bh] = rmn[0]; ams[bh] = rmx[0] - rmn[0]; }
}

// ---------------- channel attention (MFMA over l) ----------------
__global__ __launch_bounds__(256) void attn_k(const bf16* __restrict__ q, const bf16* __restrict__ k,
                                              float* __restrict__ part){
  __shared__ float red[4 * 4096];
  int ls = blockIdx.x, bh = blockIdx.y;
  int b = bh >> 3, h = bh & 7;
  int t = threadIdx.x;
  int w = t >> 6, lane = t & 63, r15 = lane & 15, g = lane >> 4;
  const bf16* qp = q + (size_t)b * CC * LL + (size_t)h * HDIM * LL;
  const bf16* kp = k + (size_t)b * CC * LL + (size_t)h * HDIM * LL;
  int kbase = ls * 1152 + w * 288;
  f32x4 acc[4][4];
  #pragma unroll
  for (int i = 0; i < 4; i++)
    #pragma unroll
    for (int j = 0; j < 4; j++) acc[i][j] = (f32x4){0.f,0.f,0.f,0.f};
  for (int ks = 0; ks < 9; ks++){
    int koff = kbase + ks * 32 + g * 8;
    short8v aq[4], bk[4];
    #pragma unroll
    for (int i = 0; i < 4; i++) aq[i] = *reinterpret_cast<const short8v*>(qp + (size_t)(i * 16 + r15) * LL + koff);
    #pragma unroll
    for (int j = 0; j < 4; j++) bk[j] = *reinterpret_cast<const short8v*>(kp + (size_t)(j * 16 + r15) * LL + koff);
    #pragma unroll
    for (int i = 0; i < 4; i++)
      #pragma unroll
      for (int j = 0; j < 4; j++)
        acc[i][j] = __builtin_amdgcn_mfma_f32_16x16x32_bf16(aq[i], bk[j], acc[i][j], 0, 0, 0);
  }
  #pragma unroll
  for (int i = 0; i < 4; i++)
    #pragma unroll
    for (int j = 0; j < 4; j++)
      #pragma unroll
      for (int e = 0; e < 4; e++)
        red[w * 4096 + (i * 16 + g * 4 + e) * 64 + j * 16 + r15] = acc[i][j][e];
  __syncthreads();
  #pragma unroll
  for (int it = 0; it < 16; it++){
    int idx = t + it * 256;
    part[((size_t)(bh * LSPLIT + ls)) * 4096 + idx] = red[idx] + red[4096 + idx] + red[8192 + idx] + red[12288 + idx];
  }
}

__global__ void smax_k(const float* __restrict__ part, const float* __restrict__ qn,
                       const float* __restrict__ kn, const float* __restrict__ scale,
                       bf16* __restrict__ Pb){
  __shared__ float As[64 * 65];
  int bh = blockIdx.x;
  int h = bh & 7;
  int tid = threadIdx.x;
  #pragma unroll
  for (int i = 0; i < 16; i++){
    int cell = tid + i * 256;
    int d = cell >> 6, e = cell & 63;
    float s = 0.f;
    #pragma unroll
    for (int ls = 0; ls < LSPLIT; ls++) s += part[((size_t)(bh * LSPLIT + ls)) * 4096 + cell];
    As[d * 65 + e] = s * scale[h] / (qn[bh * 64 + d] * kn[bh * 64 + e]);
  }
  __syncthreads();
  if (tid < 64){
    int d = tid;
    float mx = -1e30f;
    for (int e = 0; e < 64; e++) mx = fmaxf(mx, As[d * 65 + e]);
    float sum = 0.f;
    for (int e = 0; e < 64; e++){ float ev = expf(As[d * 65 + e] - mx); As[d * 65 + e] = ev; sum += ev; }
    float inv = 1.0f / sum;
    for (int e = 0; e < 64; e++) Pb[(size_t)bh * 4096 + d * 64 + e] = f2bf(As[d * 65 + e] * inv);
  }
}

// ---------------- pv (MFMA): gm recompute + softmax-combine + P@v * w[l] ----------------
__global__ __launch_bounds__(256) void pv_k(const bf16* __restrict__ q, const bf16* __restrict__ gnb,
      const float* __restrict__ aux,
      const float* __restrict__ gmin, const float* __restrict__ gms,
      const float* __restrict__ amin, const float* __restrict__ ams,
      const bf16* __restrict__ Pb, const bf16* __restrict__ vT, bf16* __restrict__ outT){
  __shared__ bf16 qs[64 * 68];
  __shared__ float sspart[4][64];
  __shared__ float rq[64];
  __shared__ float gminS[128], rgmsS[128];
  __shared__ float separt[4][64], setpart[4][64];
  __shared__ float wl[64];
  int bh = blockIdx.x, lt = blockIdx.y;
  int l0 = lt * 64;
  int t = threadIdx.x;
  int b = bh >> 3, h = bh & 7;
  int w = t >> 6, lane = t & 63, r15 = lane & 15, g = lane >> 4;
  if (t < 128){ gminS[t] = gmin[bh * 128 + t]; rgmsS[t] = 1.0f / gms[bh * 128 + t]; }
  const bf16* qp = q + (size_t)b * CC * LL + (size_t)h * HDIM * LL + l0;
  #pragma unroll
  for (int i2 = 0; i2 < 4; i2++){
    int idx = t + i2 * 256;
    int d = idx >> 4, lch = (idx & 15) * 4;
    short4v vv = *reinterpret_cast<const short4v*>(qp + (size_t)d * LL + lch);
    *(short4v*)&qs[d * 68 + lch] = vv;
  }
  __syncthreads();
  {
    int l = t & 63, dg = t >> 6;
    float ss = 0.f;
    #pragma unroll
    for (int dd = 0; dd < 16; dd++){ float v = bf2f(qs[(dg * 16 + dd) * 68 + l]); ss += v * v; }
    sspart[dg][l] = ss;
  }
  __syncthreads();
  if (t < 64){
    float ss = sspart[0][t] + sspart[1][t] + sspart[2][t] + sspart[3][t];
    rq[t] = 1.0f / fmaxf(sqrtf(ss), 1e-12f);
  }
  __syncthreads();
  short8v ag[2][2];
  #pragma unroll
  for (int i = 0; i < 2; i++)
    #pragma unroll
    for (int kt = 0; kt < 2; kt++)
      ag[i][kt] = *reinterpret_cast<const short8v*>(gnb + (size_t)(w * 32 + i * 16 + r15) * CC + h * 64 + kt * 32 + g * 8);
  short8v bq[4][2];
  #pragma unroll
  for (int j = 0; j < 4; j++){
    float rqv = rq[j * 16 + r15];
    #pragma unroll
    for (int kt = 0; kt < 2; kt++){
      short8v bb;
      #pragma unroll
      for (int jj = 0; jj < 8; jj++){
        int d = kt * 32 + g * 8 + jj;
        bb[jj] = bfbits(bf2f(qs[d * 68 + j * 16 + r15]) * rqv);
      }
      bq[j][kt] = bb;
    }
  }
  f32x4 acc[2][4];
  #pragma unroll
  for (int i = 0; i < 2; i++)
    #pragma unroll
    for (int j = 0; j < 4; j++) acc[i][j] = (f32x4){0.f,0.f,0.f,0.f};
  #pragma unroll
  for (int kt = 0; kt < 2; kt++)
    #pragma unroll
    for (int i = 0; i < 2; i++)
      #pragma unroll
      for (int j = 0; j < 4; j++)
        acc[i][j] = __builtin_amdgcn_mfma_f32_16x16x32_bf16(ag[i][kt], bq[j][kt], acc[i][j], 0, 0, 0);
  float seL[4] = {0.f,0.f,0.f,0.f}, setL[4] = {0.f,0.f,0.f,0.f};
  #pragma unroll
  for (int i = 0; i < 2; i++)
    #pragma unroll
    for (int j = 0; j < 4; j++)
      #pragma unroll
      for (int e = 0; e < 4; e++){
        int n = w * 32 + i * 16 + g * 4 + e;
        float tt = (acc[i][j][e] - gminS[n]) * rgmsS[n];
        float ee = __expf(tt);
        seL[j] += ee; setL[j] += ee * tt;
      }
  #pragma unroll
  for (int j = 0; j < 4; j++){
    seL[j] += __shfl_xor(seL[j], 16); seL[j] += __shfl_xor(seL[j], 32);
    setL[j] += __shfl_xor(setL[j], 16); setL[j] += __shfl_xor(setL[j], 32);
  }
  if (g == 0){
    #pragma unroll
    for (int j = 0; j < 4; j++){ separt[w][j * 16 + r15] = seL[j]; setpart[w][j * 16 + r15] = setL[j]; }
  }
  __syncthreads();
  if (t < 64){
    float se = separt[0][t] + separt[1][t] + separt[2][t] + separt[3][t];
    float st = setpart[0][t] + setpart[1][t] + setpart[2][t] + setpart[3][t];
    float gmred = st / se;
    float auxn = (aux[(size_t)bh * LL + l0 + t] - amin[bh]) / ams[bh];
    wl[t] = gmred * auxn;
  }
  __syncthreads();
  short8v ap[4][2];
  #pragma unroll
  for (int i = 0; i < 4; i++)
    #pragma unroll
    for (int kt = 0; kt < 2; kt++)
      ap[i][kt] = *reinterpret_cast<const short8v*>(Pb + (size_t)bh * 4096 + (i * 16 + r15) * 64 + kt * 32 + g * 8);
  const bf16* vrow = vT + ((size_t)b * LL + l0 + w * 16 + r15) * CC + h * 64;
  short8v bv[2];
  #pragma unroll
  for (int kt = 0; kt < 2; kt++) bv[kt] = *reinterpret_cast<const short8v*>(vrow + kt * 32 + g * 8);
  f32x4 oacc[4];
  #pragma unroll
  for (int i = 0; i < 4; i++) oacc[i] = (f32x4){0.f,0.f,0.f,0.f};
  #pragma unroll
  for (int kt = 0; kt < 2; kt++)
    #pragma unroll
    for (int i = 0; i < 4; i++)
      oacc[i] = __builtin_amdgcn_mfma_f32_16x16x32_bf16(ap[i][kt], bv[kt], oacc[i], 0, 0, 0);
  float wlv = wl[w * 16 + r15];
  bf16* orow = outT + ((size_t)b * LL + l0 + w * 16 + r15) * CC + h * 64;
  #pragma unroll
  for (int i = 0; i < 4; i++){
    short4v pk;
    #pragma unroll
    for (int e = 0; e < 4; e++) pk[e] = bfbits(oacc[i][e] * wlv);
    *(short4v*)&orow[i * 16 + g * 4] = pk;
  }
}

extern "C" void kernel_launch(void* const* d_in, const int* in_sizes, int n_in,
                              void* d_out, int out_size, void* d_ws, size_t ws_size,
                              hipStream_t stream){
  const float* img        = (const float*)d_in[0];
  const float* cls_embs   = (const float*)d_in[1];
  const float* cls_logits = (const float*)d_in[2];
  const float* seg        = (const float*)d_in[3];
  const float* gamma_g    = (const float*)d_in[4];
  const float* beta_g     = (const float*)d_in[5];
  const float* gamma_f    = (const float*)d_in[6];
  const float* beta_f     = (const float*)d_in[7];
  const float* attn_scale = (const float*)d_in[8];
  const float* Wg         = (const float*)d_in[9];
  const float* Wqkv       = (const float*)d_in[10];
  const float* Wo         = (const float*)d_in[11];
  const float* bo         = (const float*)d_in[12];
  const float* gamma_n    = (const float*)d_in[13];
  const float* beta_n     = (const float*)d_in[14];
  const float* W1         = (const float*)d_in[15];
  const float* b1         = (const float*)d_in[16];
  const float* W2         = (const float*)d_in[17];
  const float* b2         = (const float*)d_in[18];
  float* outp = (float*)d_out;
  (void)in_sizes; (void)n_in; (void)out_size;

  char* wsb = (char*)d_ws;
  size_t off = 0;
  auto alloc = [&](size_t bytes)->char*{
    char* p = wsb + off;
    off += (bytes + 255) & ~(size_t)255;
    return p;
  };
  float* mu1   = (float*)alloc((size_t)BLPIX * 4);
  float* rs1   = (float*)alloc((size_t)BLPIX * 4);
  float2* statp= (float2*)alloc((size_t)4 * BLPIX * 8);
  float* qn    = (float*)alloc(2048 * 4);
  float* kn    = (float*)alloc(2048 * 4);
  float* gbuf  = (float*)alloc((size_t)NCLS * CC * 4);
  bf16*  gnbb  = (bf16*)alloc((size_t)NCLS * CC * 2);
  float* clsov = (float*)alloc(2048 * 4);
  float* segn  = (float*)alloc(2048 * 4);
  float* segd  = (float*)alloc(256);
  float* objv  = (float*)alloc(2048 * 4);
  float* gminp = (float*)alloc((size_t)32 * 128 * GMBLK * 4);
  float* gmaxp = (float*)alloc((size_t)32 * 128 * GMBLK * 4);
  float* gminv = (float*)alloc(4096 * 4);
  float* gmsv  = (float*)alloc(4096 * 4);
  float* auxv  = (float*)alloc((size_t)32 * LL * 4);
  float* apmin = (float*)alloc(32 * AUXBLK * 4);
  float* apmax = (float*)alloc(32 * AUXBLK * 4);
  float* aminv = (float*)alloc(256);
  float* amsv  = (float*)alloc(256);
  bf16*  Pb    = (bf16*)alloc((size_t)32 * 4096 * 2);
  float* apart = (float*)alloc((size_t)32 * LSPLIT * 4096 * 4);
  bf16* qb    = (bf16*)alloc((size_t)BB * CC * LL * 2);
  bf16* kb    = (bf16*)alloc((size_t)BB * CC * LL * 2);
  bf16* wqkvb = (bf16*)alloc((size_t)1536 * 512 * 2);
  bf16* wob   = (bf16*)alloc((size_t)512 * 512 * 2);
  bf16* w1b   = (bf16*)alloc((size_t)512 * 512 * 2);
  bf16* w2b   = (bf16*)alloc((size_t)512 * 512 * 2);
  // d_out partitioning (bf16 halves) — both dead before MODE3 writes d_out:
  bf16* vT  = (bf16*)d_out;                                       // v [pixel][c]
  bf16* xnT = (bf16*)((char*)d_out + (size_t)BB * CC * LL * 2);   // LN(img)^T [pixel][c]
  // ws aliases (disjoint lifetimes):
  bf16* outT = kb;   // attention output [pixel][c] (k dead after attn/aux/seg)
  bf16* xT   = qb;   // x bf16 [pixel][c] (q dead after pv_k)
  bf16* hbT  = kb;   // MLP hidden [pixel][c] (outT dead after MODE1)
  if (off > ws_size) return;

  ln_stats_k<<<BLPIX / 256, 256, 0, stream>>>(img, mu1, rs1);
  wcast_k<<<1536, 256, 0, stream>>>(Wqkv, Wo, W1, W2, wqkvb, wob, w1b, w2b);
  lnT_k<<<dim3(8, 576), 256, 0, stream>>>(img, mu1, rs1, gamma_f, beta_f, xnT);
  mgemm_k<0><<<dim3(12, 288), 256, 0, stream>>>(wqkvb, xnT, nullptr, nullptr, nullptr,
      nullptr, nullptr, nullptr, nullptr, nullptr, qb, kb, vT, nullptr, nullptr, nullptr);
  rownorm_k<<<4096, 256, 0, stream>>>(qb, kb, qn, kn);
  clsg_k<<<NCLS, 256, 0, stream>>>(cls_embs, gamma_g, beta_g, Wg, gbuf, gnbb);
  clsobj_k<<<8, 256, 0, stream>>>(gbuf, cls_logits, clsov);
  gm1_k<<<dim3(32, GMBLK), 256, 0, stream>>>(qb, gnbb, gminp, gmaxp);
  gmred_k<<<4096, 64, 0, stream>>>(gminp, gmaxp, gminv, gmsv);
  seg_k<<<2048, 256, 0, stream>>>(seg, kb, segn);
  segden_k<<<BB, 256, 0, stream>>>(seg, segd);
  obj_k<<<1, 256, 0, stream>>>(clsov, segn, segd, objv);
  aux_k<<<dim3(32, AUXBLK), 256, 0, stream>>>(kb, objv, auxv, apmin, apmax);
  auxred_k<<<32, 64, 0, stream>>>(apmin, apmax, aminv, amsv);
  attn_k<<<dim3(LSPLIT, 32), 256, 0, stream>>>(qb, kb, apart);
  smax_k<<<32, 256, 0, stream>>>(apart, qn, kn, attn_scale, Pb);
  pv_k<<<dim3(32, GMBLK), 256, 0, stream>>>(qb, gnbb, auxv, gminv, gmsv, aminv, amsv, Pb, vT, outT);
  // x = img + Wo@outT + bo  -> xT bf16 + fused LN stats
  mgemm_k<1><<<dim3(4, 288), 256, 0, stream>>>(wob, outT, img, nullptr, bo,
      nullptr, nullptr, nullptr, nullptr, statp, nullptr, nullptr, nullptr, xT, nullptr, nullptr);
  statsred_k<<<BLPIX / 256, 256, 0, stream>>>(statp, mu1, rs1);
  // h = gelu(W1 @ LN(xT) + b1), LN applied inline during staging
  mgemm_k<2><<<dim3(4, 288), 256, 0, stream>>>(w1b, xT, nullptr, nullptr, b1,
      mu1, rs1, gamma_n, beta_n, nullptr, nullptr, nullptr, nullptr, nullptr, nullptr, hbT);
  // out = xT + W2 @ h + b2
  mgemm_k<3><<<dim3(4, 288), 256, 0, stream>>>(w2b, hbT, nullptr, xT, b2,
      nullptr, nullptr, nullptr, nullptr, nullptr, nullptr, nullptr, nullptr, nullptr, outp, nullptr);
}

// Round 7
// 463.827 us; speedup vs baseline: 4.8488x; 1.0729x over previous
//
#include <hip/hip_runtime.h>
#include <hip/hip_bf16.h>
#include <math.h>

#define BB 4
#define CC 512
#define NHEAD 8
#define HDIM 64
#define NCLS 128
#define DD 768
#define LL 9216
#define BLPIX 36864
#define EPSV 1e-5f
#define GMBLK 144
#define AUXBLK 36
#define LSPLIT 8
#define NLT 72   // l-tiles of 128 per batch

typedef __hip_bfloat16 bf16;
typedef __attribute__((ext_vector_type(8))) short short8v;
typedef __attribute__((ext_vector_type(4))) short short4v;
typedef __attribute__((ext_vector_type(4))) float f32x4;

__device__ __forceinline__ float bf2f(bf16 v){ return __bfloat162float(v); }
__device__ __forceinline__ bf16 f2bf(float v){ return __float2bfloat16(v); }
__device__ __forceinline__ short bfbits(float v){ bf16 b = __float2bfloat16(v); return *reinterpret_cast<short*>(&b); }
__device__ __forceinline__ float s2f(short s){ bf16 b = *reinterpret_cast<bf16*>(&s); return __bfloat162float(b); }

// ---------------- fused LN stats + apply + transpose ----------------
// reads img [b][c][l] fp32; writes xnT = LN(img)^T [pixel][c] bf16
__global__ __launch_bounds__(256) void fuse_ln_k(const float* __restrict__ X,
    const float* __restrict__ lng, const float* __restrict__ lnb,
    bf16* __restrict__ xnT){
  __shared__ float sred[2][4][64];
  __shared__ float muS[64], rsS[64];
  __shared__ float t[64][65];
  int p0 = blockIdx.x * 64;
  int b = p0 / LL, l0 = p0 - b * LL;
  int tid = threadIdx.x;
  int cg = tid >> 6, l = tid & 63;
  const float* base = X + (size_t)b * CC * LL + l0 + l;
  float s = 0.f, ss = 0.f;
  for (int c = cg * 128; c < cg * 128 + 128; c++){
    float v = base[(size_t)c * LL];
    s += v; ss += v * v;
  }
  sred[0][cg][l] = s; sred[1][cg][l] = ss;
  __syncthreads();
  if (tid < 64){
    float st = sred[0][0][tid] + sred[0][1][tid] + sred[0][2][tid] + sred[0][3][tid];
    float sst = sred[1][0][tid] + sred[1][1][tid] + sred[1][2][tid] + sred[1][3][tid];
    float m = st * (1.0f / CC);
    float var = sst * (1.0f / CC) - m * m;
    muS[tid] = m; rsS[tid] = rsqrtf(var + EPSV);
  }
  __syncthreads();
  int pr = tid >> 4;
  int cc = (tid & 15) * 4;
  for (int cb = 0; cb < 8; cb++){
    int c0 = cb * 64;
    #pragma unroll
    for (int i = 0; i < 16; i++){
      int idx = i * 256 + tid;
      int cl = idx >> 6, ll2 = idx & 63;
      t[cl][ll2] = X[(size_t)b * CC * LL + (size_t)(c0 + cl) * LL + l0 + ll2];
    }
    __syncthreads();
    #pragma unroll
    for (int i = 0; i < 4; i++){
      int pl = pr + i * 16;
      int p = p0 + pl;
      float m = muS[pl], r = rsS[pl];
      short4v pk;
      #pragma unroll
      for (int e = 0; e < 4; e++){
        int c = c0 + cc + e;
        pk[e] = bfbits((t[cc + e][pl] - m) * r * lng[c] + lnb[c]);
      }
      *(short4v*)&xnT[(size_t)p * CC + c0 + cc] = pk;
    }
    __syncthreads();
  }
}

// ---------------- weights fp32 -> bf16 ----------------
__global__ void wcast_k(const float* __restrict__ wqkv, const float* __restrict__ wo,
                        const float* __restrict__ w1, const float* __restrict__ w2,
                        bf16* __restrict__ oq, bf16* __restrict__ oo,
                        bf16* __restrict__ o1, bf16* __restrict__ o2){
  int i = blockIdx.x * 256 + threadIdx.x;
  int e = i * 4;
  const float* src; bf16* dst; int off;
  if (e < 786432){ src = wqkv; dst = oq; off = e; }
  else if (e < 1048576){ src = wo; dst = oo; off = e - 786432; }
  else if (e < 1310720){ src = w1; dst = o1; off = e - 1048576; }
  else { src = w2; dst = o2; off = e - 1310720; }
  float4 v = *reinterpret_cast<const float4*>(src + off);
  short4v pk;
  pk[0] = bfbits(v.x); pk[1] = bfbits(v.y); pk[2] = bfbits(v.z); pk[3] = bfbits(v.w);
  *(short4v*)&dst[off] = pk;
}

// ---------------- stats reduce: statp[4][BLPIX] -> mu, rs ----------------
__global__ void statsred_k(const float2* __restrict__ statp, float* __restrict__ mu, float* __restrict__ rs){
  int p = blockIdx.x * 256 + threadIdx.x;
  if (p >= BLPIX) return;
  float s = 0.f, ss = 0.f;
  #pragma unroll
  for (int part = 0; part < 4; part++){
    float2 v = statp[part * BLPIX + p];
    s += v.x; ss += v.y;
  }
  float m = s * (1.0f / CC);
  float var = ss * (1.0f / CC) - m * m;
  mu[p] = m; rs[p] = rsqrtf(var + EPSV);
}

// ---------------- rownorm reduce: [2048][NLT] partial ss -> qn/kn ----------------
__global__ void rownorm_red_k(const float* __restrict__ qssp, const float* __restrict__ kssp,
                              float* __restrict__ qn, float* __restrict__ kn){
  int row = blockIdx.x;
  const float* src = (row < 2048) ? qssp : kssp;
  int r = (row < 2048) ? row : row - 2048;
  float s = 0.f;
  for (int i = threadIdx.x; i < NLT; i += 64) s += src[(size_t)r * NLT + i];
  #pragma unroll
  for (int m = 1; m < 64; m <<= 1) s += __shfl_xor(s, m);
  if (threadIdx.x == 0){
    float nv = fmaxf(sqrtf(s), 1e-12f);
    if (row < 2048) qn[r] = nv; else kn[r] = nv;
  }
}

// ---------------- bf16 MFMA GEMM: C[M][N] = A[M][512] @ B[N][512]^T ----------------
// MODE 0: q/k [b][c][l] bf16 (+ rownorm ss partials), v -> vT [pixel][c] bf16
// MODE 1: xT = bf16(img + C + bo) [pixel][c] + fused LN stats partials (residf = img fp32)
// MODE 2: h = gelu(C+b1) bf16 [pixel][c], B = xT with inline LN
// MODE 3: d_out = xT + C + b2 (fp32 [b][c][l])
template<int MODE>
__global__ __launch_bounds__(256, 2) void mgemm_k(
    const bf16* __restrict__ A,
    const bf16* __restrict__ B,
    const float* __restrict__ residf,   // MODE1: img fp32
    const bf16* __restrict__ residb,    // MODE3: xT bf16
    const float* __restrict__ bias,
    const float* __restrict__ mu, const float* __restrict__ rs,
    const float* __restrict__ lng, const float* __restrict__ lnb,  // MODE2 LN
    float2* __restrict__ statp,         // MODE1 stats partials
    float* __restrict__ qssp, float* __restrict__ kssp,            // MODE0 rownorm partials
    bf16* __restrict__ qo, bf16* __restrict__ ko, bf16* __restrict__ vo,
    bf16* __restrict__ xT_out,
    float* __restrict__ xo,
    bf16* __restrict__ ho)
{
  __shared__ short Asm[128 * 64];
  __shared__ short Bsm[128 * 64];
  __shared__ float sredf[512];
  int tid = threadIdx.x;
  int lane = tid & 63, wv = tid >> 6;
  int wr = wv >> 1, wc = wv & 1;
  int r15 = lane & 15, g = lane >> 4, h7 = lane & 7;
  int gx = gridDim.x;
  int flat = blockIdx.y * gx + blockIdx.x;
  int cpx = (gx * gridDim.y) >> 3;
  int swz = (flat & 7) * cpx + (flat >> 3);
  int m0 = (swz % gx) * 128, n0 = (swz / gx) * 128;
  int srow = tid >> 3, skkg = tid & 7;
  int sslot = ((skkg ^ (srow & 7))) * 8;

  f32x4 acc[4][4];
  #pragma unroll
  for (int i = 0; i < 4; i++)
    #pragma unroll
    for (int j = 0; j < 4; j++) acc[i][j] = (f32x4){0.f, 0.f, 0.f, 0.f};

  short8v pa[4], pb[4];
  auto loadAB = [&](int it){
    int k0 = it * 64;
    if (MODE == 2){
      int c0 = k0 + skkg * 8;
      float ga[8], be[8];
      *(float4*)&ga[0] = *(const float4*)&lng[c0];
      *(float4*)&ga[4] = *(const float4*)&lng[c0 + 4];
      *(float4*)&be[0] = *(const float4*)&lnb[c0];
      *(float4*)&be[4] = *(const float4*)&lnb[c0 + 4];
      #pragma unroll
      for (int r = 0; r < 4; r++){
        pa[r] = *reinterpret_cast<const short8v*>(A + (size_t)(m0 + r * 32 + srow) * 512 + c0);
        int rp = n0 + r * 32 + srow;
        float mm = mu[rp], rr = rs[rp];
        short8v raw = *reinterpret_cast<const short8v*>(B + (size_t)rp * 512 + c0);
        short8v ov;
        #pragma unroll
        for (int e = 0; e < 8; e++){
          float v = (s2f(raw[e]) - mm) * rr * ga[e] + be[e];
          ov[e] = bfbits(v);
        }
        pb[r] = ov;
      }
    } else {
      #pragma unroll
      for (int r = 0; r < 4; r++){
        pa[r] = *reinterpret_cast<const short8v*>(A + (size_t)(m0 + r * 32 + srow) * 512 + k0 + skkg * 8);
        pb[r] = *reinterpret_cast<const short8v*>(B + (size_t)(n0 + r * 32 + srow) * 512 + k0 + skkg * 8);
      }
    }
  };

  loadAB(0);
  for (int it = 0; it < 8; ++it){
    __syncthreads();
    #pragma unroll
    for (int r = 0; r < 4; r++){
      int row = r * 32 + srow;
      *(short8v*)&Asm[row * 64 + sslot] = pa[r];
      *(short8v*)&Bsm[row * 64 + sslot] = pb[r];
    }
    __syncthreads();
    if (it < 7) loadAB(it + 1);
    #pragma unroll
    for (int s = 0; s < 2; s++){
      int slot = ((s * 4 + g) ^ h7) * 8;
      short8v af[4], bf_[4];
      #pragma unroll
      for (int i = 0; i < 4; i++){
        af[i]  = *(const short8v*)&Asm[(wr * 64 + i * 16 + r15) * 64 + slot];
        bf_[i] = *(const short8v*)&Bsm[(wc * 64 + i * 16 + r15) * 64 + slot];
      }
      #pragma unroll
      for (int i = 0; i < 4; i++)
        #pragma unroll
        for (int j = 0; j < 4; j++){
          if (MODE == 2)
            acc[i][j] = __builtin_amdgcn_mfma_f32_16x16x32_bf16(bf_[i], af[j], acc[i][j], 0, 0, 0);
          else
            acc[i][j] = __builtin_amdgcn_mfma_f32_16x16x32_bf16(af[i], bf_[j], acc[i][j], 0, 0, 0);
        }
    }
  }

  int bIdx = n0 / LL;
  int lbase = n0 - bIdx * LL;
  if (MODE == 0){
    int part = m0 >> 9;
    if (part < 2){
      bf16* dst = (part == 0) ? qo : ko;
      int chb = (m0 & 511) + wr * 64;
      #pragma unroll
      for (int i = 0; i < 4; i++)
        #pragma unroll
        for (int j = 0; j < 4; j++){
          int l = lbase + wc * 64 + j * 16 + r15;
          #pragma unroll
          for (int e = 0; e < 4; e++){
            int ch = chb + i * 16 + g * 4 + e;
            dst[(size_t)bIdx * CC * LL + (size_t)ch * LL + l] = f2bf(acc[i][j][e]);
          }
        }
      // rownorm ss partials: per-channel sum of acc^2 over this tile's 128 l
      #pragma unroll
      for (int i = 0; i < 4; i++)
        #pragma unroll
        for (int e = 0; e < 4; e++){
          float ssv = acc[i][0][e]*acc[i][0][e] + acc[i][1][e]*acc[i][1][e]
                    + acc[i][2][e]*acc[i][2][e] + acc[i][3][e]*acc[i][3][e];
          #pragma unroll
          for (int msk = 1; msk < 16; msk <<= 1) ssv += __shfl_xor(ssv, msk);
          if (r15 == 0) sredf[wv * 64 + i * 16 + g * 4 + e] = ssv;
        }
      __syncthreads();
      if (tid < 128){
        int wrr = tid >> 6, chL = tid & 63;
        float tot = sredf[(wrr * 2) * 64 + chL] + sredf[(wrr * 2 + 1) * 64 + chL];
        int c = (m0 & 511) + wrr * 64 + chL;
        int row = bIdx * 512 + c;
        int ltile = lbase >> 7;
        float* dd = (part == 0) ? qssp : kssp;
        dd[(size_t)row * NLT + ltile] = tot;
      }
    } else {
      int chb = (m0 & 511) + wr * 64;
      #pragma unroll
      for (int i = 0; i < 4; i++)
        #pragma unroll
        for (int j = 0; j < 4; j++){
          int l = lbase + wc * 64 + j * 16 + r15;
          int ch = chb + i * 16 + g * 4;
          short4v pk;
          #pragma unroll
          for (int e = 0; e < 4; e++) pk[e] = bfbits(acc[i][j][e]);
          *(short4v*)&vo[((size_t)bIdx * LL + l) * CC + ch] = pk;
        }
    }
  } else if (MODE == 1){
    float sj[4] = {0.f,0.f,0.f,0.f}, ssj[4] = {0.f,0.f,0.f,0.f};
    #pragma unroll
    for (int i = 0; i < 4; i++)
      #pragma unroll
      for (int j = 0; j < 4; j++){
        int l = lbase + wc * 64 + j * 16 + r15;
        int chm = m0 + wr * 64 + i * 16 + g * 4;
        short4v pk;
        #pragma unroll
        for (int e = 0; e < 4; e++){
          int m = chm + e;
          size_t o = (size_t)bIdx * CC * LL + (size_t)m * LL + l;
          float xv = residf[o] + acc[i][j][e] + bias[m];
          pk[e] = bfbits(xv);
          sj[j] += xv; ssj[j] += xv * xv;
        }
        *(short4v*)&xT_out[((size_t)bIdx * LL + l) * CC + chm] = pk;
      }
    #pragma unroll
    for (int j = 0; j < 4; j++){
      sj[j] += __shfl_xor(sj[j], 16); sj[j] += __shfl_xor(sj[j], 32);
      ssj[j] += __shfl_xor(ssj[j], 16); ssj[j] += __shfl_xor(ssj[j], 32);
    }
    if (g == 0){
      #pragma unroll
      for (int j = 0; j < 4; j++){
        sredf[wv * 128 + j * 32 + r15 * 2 + 0] = sj[j];
        sredf[wv * 128 + j * 32 + r15 * 2 + 1] = ssj[j];
      }
    }
    __syncthreads();
    if (tid < 128){
      int wv2 = tid >> 6, lane2 = tid & 63, j2 = lane2 >> 4, r2 = lane2 & 15;
      float s   = sredf[wv2 * 128 + j2 * 32 + r2 * 2 + 0] + sredf[(wv2 + 2) * 128 + j2 * 32 + r2 * 2 + 0];
      float ss2 = sredf[wv2 * 128 + j2 * 32 + r2 * 2 + 1] + sredf[(wv2 + 2) * 128 + j2 * 32 + r2 * 2 + 1];
      int p = n0 + wv2 * 64 + j2 * 16 + r2;
      statp[(m0 >> 7) * BLPIX + p] = make_float2(s, ss2);
    }
  } else if (MODE == 3){
    #pragma unroll
    for (int i = 0; i < 4; i++)
      #pragma unroll
      for (int j = 0; j < 4; j++){
        int l = lbase + wc * 64 + j * 16 + r15;
        int chm = m0 + wr * 64 + i * 16 + g * 4;
        short4v rv = *(const short4v*)&residb[((size_t)bIdx * LL + l) * CC + chm];
        #pragma unroll
        for (int e = 0; e < 4; e++){
          int m = chm + e;
          size_t o = (size_t)bIdx * CC * LL + (size_t)m * LL + l;
          xo[o] = s2f(rv[e]) + acc[i][j][e] + bias[m];
        }
      }
  } else {
    #pragma unroll
    for (int i = 0; i < 4; i++)
      #pragma unroll
      for (int j = 0; j < 4; j++){
        int mm = m0 + wr * 64 + j * 16 + r15;
        float bv = bias[mm];
        #pragma unroll
        for (int e = 0; e < 4; e++){
          int n = n0 + wc * 64 + i * 16 + g * 4 + e;
          float t = acc[i][j][e] + bv;
          float gv = 0.5f * t * (1.0f + erff(t * 0.70710678118654752f));
          ho[(size_t)n * CC + mm] = f2bf(gv);
        }
      }
  }
}

__global__ void clsg_k(const float* __restrict__ cls_embs, const float* __restrict__ gamma_g,
                       const float* __restrict__ beta_g, const float* __restrict__ Wg,
                       float* __restrict__ g, bf16* __restrict__ gnb){
  __shared__ float cn[DD];
  __shared__ float red[256];
  __shared__ float gsh[CC];
  __shared__ float nrm[NHEAD];
  int n = blockIdx.x;
  const float* e = cls_embs + (size_t)n * DD;
  float s = 0.f, ss = 0.f;
  for (int i = threadIdx.x; i < DD; i += 256){ float v = e[i]; s += v; ss += v * v; }
  red[threadIdx.x] = s; __syncthreads();
  for (int st = 128; st > 0; st >>= 1){ if (threadIdx.x < st) red[threadIdx.x] += red[threadIdx.x + st]; __syncthreads(); }
  float mean = red[0] / DD; __syncthreads();
  red[threadIdx.x] = ss; __syncthreads();
  for (int st = 128; st > 0; st >>= 1){ if (threadIdx.x < st) red[threadIdx.x] += red[threadIdx.x + st]; __syncthreads(); }
  float var = red[0] / DD - mean * mean;
  float rstd = rsqrtf(var + EPSV);
  __syncthreads();
  for (int i = threadIdx.x; i < DD; i += 256) cn[i] = (e[i] - mean) * rstd * gamma_g[i] + beta_g[i];
  __syncthreads();
  for (int c = threadIdx.x; c < CC; c += 256){
    const float* w = Wg + (size_t)c * DD;
    float a = 0.f;
    #pragma unroll 8
    for (int d = 0; d < DD; d++) a += cn[d] * w[d];
    gsh[c] = a;
  }
  __syncthreads();
  if (threadIdx.x < NHEAD){
    float a = 0.f;
    for (int d = 0; d < HDIM; d++){ float v = gsh[threadIdx.x * HDIM + d]; a += v * v; }
    nrm[threadIdx.x] = fmaxf(sqrtf(a), 1e-12f);
  }
  __syncthreads();
  for (int c = threadIdx.x; c < CC; c += 256){
    g[(size_t)n * CC + c] = gsh[c];
    gnb[(size_t)n * CC + c] = f2bf(gsh[c] / nrm[c >> 6]);
  }
}

__global__ void clsobj_k(const float* __restrict__ g, const float* __restrict__ cls_l,
                         float* __restrict__ cls_obj){
  int idx = blockIdx.x * 256 + threadIdx.x;
  if (idx >= BB * CC) return;
  int b = idx >> 9, c = idx & 511;
  float a = 0.f;
  for (int n = 0; n < NCLS; n++) a += g[(size_t)n * CC + c] * cls_l[b * NCLS + n];
  cls_obj[idx] = a;
}

// ---------------- gm pass 1 (MFMA): per-(bh,n) min/max over l ----------------
__global__ __launch_bounds__(256) void gm1_k(const bf16* __restrict__ q, const bf16* __restrict__ gnb,
        float* __restrict__ pmin, float* __restrict__ pmax){
  __shared__ bf16 qs[64 * 68];
  __shared__ float sspart[4][64];
  __shared__ float rq[64];
  int bh = blockIdx.x, lt = blockIdx.y;
  int l0 = lt * 64;
  int t = threadIdx.x;
  int b = bh >> 3, h = bh & 7;
  int w = t >> 6, lane = t & 63, r15 = lane & 15, g = lane >> 4;
  const bf16* qp = q + (size_t)b * CC * LL + (size_t)h * HDIM * LL + l0;
  #pragma unroll
  for (int i2 = 0; i2 < 4; i2++){
    int idx = t + i2 * 256;
    int d = idx >> 4, lch = (idx & 15) * 4;
    short4v vv = *reinterpret_cast<const short4v*>(qp + (size_t)d * LL + lch);
    *(short4v*)&qs[d * 68 + lch] = vv;
  }
  __syncthreads();
  {
    int l = t & 63, dg = t >> 6;
    float ss = 0.f;
    #pragma unroll
    for (int dd = 0; dd < 16; dd++){ float v = bf2f(qs[(dg * 16 + dd) * 68 + l]); ss += v * v; }
    sspart[dg][l] = ss;
  }
  __syncthreads();
  if (t < 64){
    float ss = sspart[0][t] + sspart[1][t] + sspart[2][t] + sspart[3][t];
    rq[t] = 1.0f / fmaxf(sqrtf(ss), 1e-12f);
  }
  __syncthreads();
  short8v ag[2][2];
  #pragma unroll
  for (int i = 0; i < 2; i++)
    #pragma unroll
    for (int kt = 0; kt < 2; kt++)
      ag[i][kt] = *reinterpret_cast<const short8v*>(gnb + (size_t)(w * 32 + i * 16 + r15) * CC + h * 64 + kt * 32 + g * 8);
  short8v bq[4][2];
  #pragma unroll
  for (int j = 0; j < 4; j++){
    float rqv = rq[j * 16 + r15];
    #pragma unroll
    for (int kt = 0; kt < 2; kt++){
      short8v bb;
      #pragma unroll
      for (int jj = 0; jj < 8; jj++){
        int d = kt * 32 + g * 8 + jj;
        bb[jj] = bfbits(bf2f(qs[d * 68 + j * 16 + r15]) * rqv);
      }
      bq[j][kt] = bb;
    }
  }
  f32x4 acc[2][4];
  #pragma unroll
  for (int i = 0; i < 2; i++)
    #pragma unroll
    for (int j = 0; j < 4; j++) acc[i][j] = (f32x4){0.f,0.f,0.f,0.f};
  #pragma unroll
  for (int kt = 0; kt < 2; kt++)
    #pragma unroll
    for (int i = 0; i < 2; i++)
      #pragma unroll
      for (int j = 0; j < 4; j++)
        acc[i][j] = __builtin_amdgcn_mfma_f32_16x16x32_bf16(ag[i][kt], bq[j][kt], acc[i][j], 0, 0, 0);
  #pragma unroll
  for (int i = 0; i < 2; i++)
    #pragma unroll
    for (int e = 0; e < 4; e++){
      float mn = acc[i][0][e], mx = acc[i][0][e];
      #pragma unroll
      for (int j = 1; j < 4; j++){ mn = fminf(mn, acc[i][j][e]); mx = fmaxf(mx, acc[i][j][e]); }
      #pragma unroll
      for (int msk = 1; msk < 16; msk <<= 1){
        mn = fminf(mn, __shfl_xor(mn, msk));
        mx = fmaxf(mx, __shfl_xor(mx, msk));
      }
      if (r15 == 0){
        int n = w * 32 + i * 16 + g * 4 + e;
        pmin[((size_t)bh * 128 + n) * GMBLK + lt] = mn;
        pmax[((size_t)bh * 128 + n) * GMBLK + lt] = mx;
      }
    }
}

__global__ void gmred_k(const float* __restrict__ pmin, const float* __restrict__ pmax,
                        float* __restrict__ gmin, float* __restrict__ gms){
  __shared__ float rmn[64], rmx[64];
  int row = blockIdx.x;
  float mn = 1e30f, mx = -1e30f;
  for (int i = threadIdx.x; i < GMBLK; i += 64){
    mn = fminf(mn, pmin[(size_t)row * GMBLK + i]);
    mx = fmaxf(mx, pmax[(size_t)row * GMBLK + i]);
  }
  rmn[threadIdx.x] = mn; rmx[threadIdx.x] = mx; __syncthreads();
  for (int st = 32; st > 0; st >>= 1){
    if (threadIdx.x < st){
      rmn[threadIdx.x] = fminf(rmn[threadIdx.x], rmn[threadIdx.x + st]);
      rmx[threadIdx.x] = fmaxf(rmx[threadIdx.x], rmx[threadIdx.x + st]);
    }
    __syncthreads();
  }
  if (threadIdx.x == 0){ gmin[row] = rmn[0]; gms[row] = rmx[0] - rmn[0]; }
}

__global__ void seg_k(const float* __restrict__ seg, const bf16* __restrict__ k, float* __restrict__ seg_num){
  __shared__ float red[256];
  int bc = blockIdx.x;
  int b = bc >> 9;
  const bf16* p = k + (size_t)bc * LL;
  const float* sp = seg + (size_t)b * LL;
  float s = 0.f;
  for (int i = threadIdx.x; i < LL; i += 256){
    float m = 1.0f / (1.0f + expf(-sp[i]));
    s += m * bf2f(p[i]);
  }
  red[threadIdx.x] = s; __syncthreads();
  for (int st = 128; st > 0; st >>= 1){ if (threadIdx.x < st) red[threadIdx.x] += red[threadIdx.x + st]; __syncthreads(); }
  if (threadIdx.x == 0) seg_num[bc] = red[0];
}

__global__ void segden_k(const float* __restrict__ seg, float* __restrict__ den){
  __shared__ float red[256];
  int b = blockIdx.x;
  const float* sp = seg + (size_t)b * LL;
  float s = 0.f;
  for (int i = threadIdx.x; i < LL; i += 256) s += 1.0f / (1.0f + expf(-sp[i]));
  red[threadIdx.x] = s; __syncthreads();
  for (int st = 128; st > 0; st >>= 1){ if (threadIdx.x < st) red[threadIdx.x] += red[threadIdx.x + st]; __syncthreads(); }
  if (threadIdx.x == 0) den[b] = red[0];
}

__global__ void obj_k(const float* __restrict__ cls_obj, const float* __restrict__ seg_num,
                      const float* __restrict__ den, float* __restrict__ obj){
  __shared__ float sval[2048];
  __shared__ float nrm[32];
  int tid = threadIdx.x;
  #pragma unroll
  for (int i = 0; i < 8; i++){
    int idx = tid + i * 256;
    int b = idx >> 9;
    sval[idx] = cls_obj[idx] + seg_num[idx] / den[b];
  }
  __syncthreads();
  if (tid < 32){
    float s = 0.f;
    for (int d = 0; d < 64; d++){ float v = sval[tid * 64 + d]; s += v * v; }
    nrm[tid] = fmaxf(sqrtf(s), 1e-12f);
  }
  __syncthreads();
  #pragma unroll
  for (int i = 0; i < 8; i++){
    int idx = tid + i * 256;
    obj[idx] = sval[idx] / nrm[idx >> 6];
  }
}

__global__ void aux_k(const bf16* __restrict__ k, const float* __restrict__ obj, float* __restrict__ aux,
                      float* __restrict__ pmin, float* __restrict__ pmax){
  __shared__ float os[64];
  __shared__ float rmn[256], rmx[256];
  int bh = blockIdx.x, lt = blockIdx.y;
  int b = bh >> 3, h = bh & 7;
  int l = lt * 256 + threadIdx.x;
  if (threadIdx.x < 64) os[threadIdx.x] = obj[bh * 64 + threadIdx.x];
  __syncthreads();
  const bf16* kp = k + (size_t)b * CC * LL + (size_t)h * HDIM * LL + l;
  float ss = 0.f, dot = 0.f;
  #pragma unroll 8
  for (int d = 0; d < 64; d++){ float v = bf2f(kp[(size_t)d * LL]); ss += v * v; dot += os[d] * v; }
  float av = dot / fmaxf(sqrtf(ss), 1e-12f);
  aux[(size_t)bh * LL + l] = av;
  rmn[threadIdx.x] = av; rmx[threadIdx.x] = av; __syncthreads();
  for (int st = 128; st > 0; st >>= 1){
    if (threadIdx.x < st){
      rmn[threadIdx.x] = fminf(rmn[threadIdx.x], rmn[threadIdx.x + st]);
      rmx[threadIdx.x] = fmaxf(rmx[threadIdx.x], rmx[threadIdx.x + st]);
    }
    __syncthreads();
  }
  if (threadIdx.x == 0){ pmin[bh * AUXBLK + lt] = rmn[0]; pmax[bh * AUXBLK + lt] = rmx[0]; }
}

__global__ void auxred_k(const float* __restrict__ pmin, const float* __restrict__ pmax,
                         float* __restrict__ amin, float* __restrict__ ams){
  __shared__ float rmn[64], rmx[64];
  int bh = blockIdx.x;
  float mn = 1e30f, mx = -1e30f;
  for (int i = threadIdx.x; i < AUXBLK; i += 64){
    mn = fminf(mn, pmin[bh * AUXBLK + i]);
    mx = fmaxf(mx, pmax[bh * AUXBLK + i]);
  }
  rmn[threadIdx.x] = mn; rmx[threadIdx.x] = mx; __syncthreads();
  for (int st = 32; st > 0; st >>= 1){
    if (threadIdx.x < st){
      rmn[threadIdx.x] = fminf(rmn[threadIdx.x], rmn[threadIdx.x + st]);
      rmx[threadIdx.x] = fmaxf(rmx[threadIdx.x], rmx[threadIdx.x + st]);
    }
    __syncthreads();
  }
  if (threadIdx.x == 0){ amin[bh] = rmn[0]; ams[bh] = rmx[0] - rmn[0]; }
}

// ---------------- channel attention (MFMA over l) ----------------
__global__ __launch_bounds__(256) void attn_k(const bf16* __restrict__ q, const bf16* __restrict__ k,
                                              float* __restrict__ part){
  __shared__ float red[4 * 4096];
  int ls = blockIdx.x, bh = blockIdx.y;
  int b = bh >> 3, h = bh & 7;
  int t = threadIdx.x;
  int w = t >> 6, lane = t & 63, r15 = lane & 15, g = lane >> 4;
  const bf16* qp = q + (size_t)b * CC * LL + (size_t)h * HDIM * LL;
  const bf16* kp = k + (size_t)b * CC * LL + (size_t)h * HDIM * LL;
  int kbase = ls * 1152 + w * 288;
  f32x4 acc[4][4];
  #pragma unroll
  for (int i = 0; i < 4; i++)
    #pragma unroll
    for (int j = 0; j < 4; j++) acc[i][j] = (f32x4){0.f,0.f,0.f,0.f};
  for (int ks = 0; ks < 9; ks++){
    int koff = kbase + ks * 32 + g * 8;
    short8v aq[4], bk[4];
    #pragma unroll
    for (int i = 0; i < 4; i++) aq[i] = *reinterpret_cast<const short8v*>(qp + (size_t)(i * 16 + r15) * LL + koff);
    #pragma unroll
    for (int j = 0; j < 4; j++) bk[j] = *reinterpret_cast<const short8v*>(kp + (size_t)(j * 16 + r15) * LL + koff);
    #pragma unroll
    for (int i = 0; i < 4; i++)
      #pragma unroll
      for (int j = 0; j < 4; j++)
        acc[i][j] = __builtin_amdgcn_mfma_f32_16x16x32_bf16(aq[i], bk[j], acc[i][j], 0, 0, 0);
  }
  #pragma unroll
  for (int i = 0; i < 4; i++)
    #pragma unroll
    for (int j = 0; j < 4; j++)
      #pragma unroll
      for (int e = 0; e < 4; e++)
        red[w * 4096 + (i * 16 + g * 4 + e) * 64 + j * 16 + r15] = acc[i][j][e];
  __syncthreads();
  #pragma unroll
  for (int it = 0; it < 16; it++){
    int idx = t + it * 256;
    part[((size_t)(bh * LSPLIT + ls)) * 4096 + idx] = red[idx] + red[4096 + idx] + red[8192 + idx] + red[12288 + idx];
  }
}

__global__ void smax_k(const float* __restrict__ part, const float* __restrict__ qn,
                       const float* __restrict__ kn, const float* __restrict__ scale,
                       bf16* __restrict__ Pb){
  __shared__ float As[64 * 65];
  int bh = blockIdx.x;
  int h = bh & 7;
  int tid = threadIdx.x;
  #pragma unroll
  for (int i = 0; i < 16; i++){
    int cell = tid + i * 256;
    int d = cell >> 6, e = cell & 63;
    float s = 0.f;
    #pragma unroll
    for (int ls = 0; ls < LSPLIT; ls++) s += part[((size_t)(bh * LSPLIT + ls)) * 4096 + cell];
    As[d * 65 + e] = s * scale[h] / (qn[bh * 64 + d] * kn[bh * 64 + e]);
  }
  __syncthreads();
  if (tid < 64){
    int d = tid;
    float mx = -1e30f;
    for (int e = 0; e < 64; e++) mx = fmaxf(mx, As[d * 65 + e]);
    float sum = 0.f;
    for (int e = 0; e < 64; e++){ float ev = expf(As[d * 65 + e] - mx); As[d * 65 + e] = ev; sum += ev; }
    float inv = 1.0f / sum;
    for (int e = 0; e < 64; e++) Pb[(size_t)bh * 4096 + d * 64 + e] = f2bf(As[d * 65 + e] * inv);
  }
}

// ---------------- pv (MFMA): gm recompute + softmax-combine + P@v * w[l] ----------------
__global__ __launch_bounds__(256) void pv_k(const bf16* __restrict__ q, const bf16* __restrict__ gnb,
      const float* __restrict__ aux,
      const float* __restrict__ gmin, const float* __restrict__ gms,
      const float* __restrict__ amin, const float* __restrict__ ams,
      const bf16* __restrict__ Pb, const bf16* __restrict__ vT, bf16* __restrict__ outT){
  __shared__ bf16 qs[64 * 68];
  __shared__ float sspart[4][64];
  __shared__ float rq[64];
  __shared__ float gminS[128], rgmsS[128];
  __shared__ float separt[4][64], setpart[4][64];
  __shared__ float wl[64];
  int bh = blockIdx.x, lt = blockIdx.y;
  int l0 = lt * 64;
  int t = threadIdx.x;
  int b = bh >> 3, h = bh & 7;
  int w = t >> 6, lane = t & 63, r15 = lane & 15, g = lane >> 4;
  if (t < 128){ gminS[t] = gmin[bh * 128 + t]; rgmsS[t] = 1.0f / gms[bh * 128 + t]; }
  const bf16* qp = q + (size_t)b * CC * LL + (size_t)h * HDIM * LL + l0;
  #pragma unroll
  for (int i2 = 0; i2 < 4; i2++){
    int idx = t + i2 * 256;
    int d = idx >> 4, lch = (idx & 15) * 4;
    short4v vv = *reinterpret_cast<const short4v*>(qp + (size_t)d * LL + lch);
    *(short4v*)&qs[d * 68 + lch] = vv;
  }
  __syncthreads();
  {
    int l = t & 63, dg = t >> 6;
    float ss = 0.f;
    #pragma unroll
    for (int dd = 0; dd < 16; dd++){ float v = bf2f(qs[(dg * 16 + dd) * 68 + l]); ss += v * v; }
    sspart[dg][l] = ss;
  }
  __syncthreads();
  if (t < 64){
    float ss = sspart[0][t] + sspart[1][t] + sspart[2][t] + sspart[3][t];
    rq[t] = 1.0f / fmaxf(sqrtf(ss), 1e-12f);
  }
  __syncthreads();
  short8v ag[2][2];
  #pragma unroll
  for (int i = 0; i < 2; i++)
    #pragma unroll
    for (int kt = 0; kt < 2; kt++)
      ag[i][kt] = *reinterpret_cast<const short8v*>(gnb + (size_t)(w * 32 + i * 16 + r15) * CC + h * 64 + kt * 32 + g * 8);
  short8v bq[4][2];
  #pragma unroll
  for (int j = 0; j < 4; j++){
    float rqv = rq[j * 16 + r15];
    #pragma unroll
    for (int kt = 0; kt < 2; kt++){
      short8v bb;
      #pragma unroll
      for (int jj = 0; jj < 8; jj++){
        int d = kt * 32 + g * 8 + jj;
        bb[jj] = bfbits(bf2f(qs[d * 68 + j * 16 + r15]) * rqv);
      }
      bq[j][kt] = bb;
    }
  }
  f32x4 acc[2][4];
  #pragma unroll
  for (int i = 0; i < 2; i++)
    #pragma unroll
    for (int j = 0; j < 4; j++) acc[i][j] = (f32x4){0.f,0.f,0.f,0.f};
  #pragma unroll
  for (int kt = 0; kt < 2; kt++)
    #pragma unroll
    for (int i = 0; i < 2; i++)
      #pragma unroll
      for (int j = 0; j < 4; j++)
        acc[i][j] = __builtin_amdgcn_mfma_f32_16x16x32_bf16(ag[i][kt], bq[j][kt], acc[i][j], 0, 0, 0);
  float seL[4] = {0.f,0.f,0.f,0.f}, setL[4] = {0.f,0.f,0.f,0.f};
  #pragma unroll
  for (int i = 0; i < 2; i++)
    #pragma unroll
    for (int j = 0; j < 4; j++)
      #pragma unroll
      for (int e = 0; e < 4; e++){
        int n = w * 32 + i * 16 + g * 4 + e;
        float tt = (acc[i][j][e] - gminS[n]) * rgmsS[n];
        float ee = __expf(tt);
        seL[j] += ee; setL[j] += ee * tt;
      }
  #pragma unroll
  for (int j = 0; j < 4; j++){
    seL[j] += __shfl_xor(seL[j], 16); seL[j] += __shfl_xor(seL[j], 32);
    setL[j] += __shfl_xor(setL[j], 16); setL[j] += __shfl_xor(setL[j], 32);
  }
  if (g == 0){
    #pragma unroll
    for (int j = 0; j < 4; j++){ separt[w][j * 16 + r15] = seL[j]; setpart[w][j * 16 + r15] = setL[j]; }
  }
  __syncthreads();
  if (t < 64){
    float se = separt[0][t] + separt[1][t] + separt[2][t] + separt[3][t];
    float st = setpart[0][t] + setpart[1][t] + setpart[2][t] + setpart[3][t];
    float gmred = st / se;
    float auxn = (aux[(size_t)bh * LL + l0 + t] - amin[bh]) / ams[bh];
    wl[t] = gmred * auxn;
  }
  __syncthreads();
  short8v ap[4][2];
  #pragma unroll
  for (int i = 0; i < 4; i++)
    #pragma unroll
    for (int kt = 0; kt < 2; kt++)
      ap[i][kt] = *reinterpret_cast<const short8v*>(Pb + (size_t)bh * 4096 + (i * 16 + r15) * 64 + kt * 32 + g * 8);
  const bf16* vrow = vT + ((size_t)b * LL + l0 + w * 16 + r15) * CC + h * 64;
  short8v bv[2];
  #pragma unroll
  for (int kt = 0; kt < 2; kt++) bv[kt] = *reinterpret_cast<const short8v*>(vrow + kt * 32 + g * 8);
  f32x4 oacc[4];
  #pragma unroll
  for (int i = 0; i < 4; i++) oacc[i] = (f32x4){0.f,0.f,0.f,0.f};
  #pragma unroll
  for (int kt = 0; kt < 2; kt++)
    #pragma unroll
    for (int i = 0; i < 4; i++)
      oacc[i] = __builtin_amdgcn_mfma_f32_16x16x32_bf16(ap[i][kt], bv[kt], oacc[i], 0, 0, 0);
  float wlv = wl[w * 16 + r15];
  bf16* orow = outT + ((size_t)b * LL + l0 + w * 16 + r15) * CC + h * 64;
  #pragma unroll
  for (int i = 0; i < 4; i++){
    short4v pk;
    #pragma unroll
    for (int e = 0; e < 4; e++) pk[e] = bfbits(oacc[i][e] * wlv);
    *(short4v*)&orow[i * 16 + g * 4] = pk;
  }
}

extern "C" void kernel_launch(void* const* d_in, const int* in_sizes, int n_in,
                              void* d_out, int out_size, void* d_ws, size_t ws_size,
                              hipStream_t stream){
  const float* img        = (const float*)d_in[0];
  const float* cls_embs   = (const float*)d_in[1];
  const float* cls_logits = (const float*)d_in[2];
  const float* seg        = (const float*)d_in[3];
  const float* gamma_g    = (const float*)d_in[4];
  const float* beta_g     = (const float*)d_in[5];
  const float* gamma_f    = (const float*)d_in[6];
  const float* beta_f     = (const float*)d_in[7];
  const float* attn_scale = (const float*)d_in[8];
  const float* Wg         = (const float*)d_in[9];
  const float* Wqkv       = (const float*)d_in[10];
  const float* Wo         = (const float*)d_in[11];
  const float* bo         = (const float*)d_in[12];
  const float* gamma_n    = (const float*)d_in[13];
  const float* beta_n     = (const float*)d_in[14];
  const float* W1         = (const float*)d_in[15];
  const float* b1         = (const float*)d_in[16];
  const float* W2         = (const float*)d_in[17];
  const float* b2         = (const float*)d_in[18];
  float* outp = (float*)d_out;
  (void)in_sizes; (void)n_in; (void)out_size;

  char* wsb = (char*)d_ws;
  size_t off = 0;
  auto alloc = [&](size_t bytes)->char*{
    char* p = wsb + off;
    off += (bytes + 255) & ~(size_t)255;
    return p;
  };
  float* mu1   = (float*)alloc((size_t)BLPIX * 4);
  float* rs1   = (float*)alloc((size_t)BLPIX * 4);
  float2* statp= (float2*)alloc((size_t)4 * BLPIX * 8);
  float* qssp  = (float*)alloc((size_t)2048 * NLT * 4);
  float* kssp  = (float*)alloc((size_t)2048 * NLT * 4);
  float* qn    = (float*)alloc(2048 * 4);
  float* kn    = (float*)alloc(2048 * 4);
  float* gbuf  = (float*)alloc((size_t)NCLS * CC * 4);
  bf16*  gnbb  = (bf16*)alloc((size_t)NCLS * CC * 2);
  float* clsov = (float*)alloc(2048 * 4);
  float* segn  = (float*)alloc(2048 * 4);
  float* segd  = (float*)alloc(256);
  float* objv  = (float*)alloc(2048 * 4);
  float* gminp = (float*)alloc((size_t)32 * 128 * GMBLK * 4);
  float* gmaxp = (float*)alloc((size_t)32 * 128 * GMBLK * 4);
  float* gminv = (float*)alloc(4096 * 4);
  float* gmsv  = (float*)alloc(4096 * 4);
  float* auxv  = (float*)alloc((size_t)32 * LL * 4);
  float* apmin = (float*)alloc(32 * AUXBLK * 4);
  float* apmax = (float*)alloc(32 * AUXBLK * 4);
  float* aminv = (float*)alloc(256);
  float* amsv  = (float*)alloc(256);
  bf16*  Pb    = (bf16*)alloc((size_t)32 * 4096 * 2);
  float* apart = (float*)alloc((size_t)32 * LSPLIT * 4096 * 4);
  bf16* qb    = (bf16*)alloc((size_t)BB * CC * LL * 2);
  bf16* kb    = (bf16*)alloc((size_t)BB * CC * LL * 2);
  bf16* wqkvb = (bf16*)alloc((size_t)1536 * 512 * 2);
  bf16* wob   = (bf16*)alloc((size_t)512 * 512 * 2);
  bf16* w1b   = (bf16*)alloc((size_t)512 * 512 * 2);
  bf16* w2b   = (bf16*)alloc((size_t)512 * 512 * 2);
  // d_out (75.5 MB fp32) partitioned into exactly two bf16 halves,
  // both dead before MODE3 writes the final fp32 output:
  bf16* vT  = (bf16*)d_out;                                       // v [pixel][c], [0, 37.75 MB)
  bf16* xnT = (bf16*)((char*)d_out + (size_t)BB * CC * LL * 2);   // LN(img)^T, [37.75, 75.5 MB)
  // ws aliases (disjoint lifetimes):
  bf16* outT = kb;   // attention output [pixel][c] (k dead after attn/aux/seg)
  bf16* xT   = qb;   // x bf16 [pixel][c] (q dead after pv_k)
  bf16* hbT  = kb;   // MLP hidden [pixel][c] (outT dead after MODE1)
  if (off > ws_size) return;

  wcast_k<<<1536, 256, 0, stream>>>(Wqkv, Wo, W1, W2, wqkvb, wob, w1b, w2b);
  fuse_ln_k<<<576, 256, 0, stream>>>(img, gamma_f, beta_f, xnT);
  mgemm_k<0><<<dim3(12, 288), 256, 0, stream>>>(wqkvb, xnT, nullptr, nullptr, nullptr,
      nullptr, nullptr, nullptr, nullptr, nullptr, qssp, kssp,
      qb, kb, vT, nullptr, nullptr, nullptr);
  rownorm_red_k<<<4096, 64, 0, stream>>>(qssp, kssp, qn, kn);
  clsg_k<<<NCLS, 256, 0, stream>>>(cls_embs, gamma_g, beta_g, Wg, gbuf, gnbb);
  clsobj_k<<<8, 256, 0, stream>>>(gbuf, cls_logits, clsov);
  gm1_k<<<dim3(32, GMBLK), 256, 0, stream>>>(qb, gnbb, gminp, gmaxp);
  gmred_k<<<4096, 64, 0, stream>>>(gminp, gmaxp, gminv, gmsv);
  seg_k<<<2048, 256, 0, stream>>>(seg, kb, segn);
  segden_k<<<BB, 256, 0, stream>>>(seg, segd);
  obj_k<<<1, 256, 0, stream>>>(clsov, segn, segd, objv);
  aux_k<<<dim3(32, AUXBLK), 256, 0, stream>>>(kb, objv, auxv, apmin, apmax);
  auxred_k<<<32, 64, 0, stream>>>(apmin, apmax, aminv, amsv);
  attn_k<<<dim3(LSPLIT, 32), 256, 0, stream>>>(qb, kb, apart);
  smax_k<<<32, 256, 0, stream>>>(apart, qn, kn, attn_scale, Pb);
  pv_k<<<dim3(32, GMBLK), 256, 0, stream>>>(qb, gnbb, auxv, gminv, gmsv, aminv, amsv, Pb, vT, outT);
  // x = img + Wo@outT + bo  -> xT bf16 + fused LN stats
  mgemm_k<1><<<dim3(4, 288), 256, 0, stream>>>(wob, outT, img, nullptr, bo,
      nullptr, nullptr, nullptr, nullptr, statp, nullptr, nullptr,
      nullptr, nullptr, nullptr, xT, nullptr, nullptr);
  statsred_k<<<BLPIX / 256, 256, 0, stream>>>(statp, mu1, rs1);
  // h = gelu(W1 @ LN(xT) + b1), LN applied inline during staging
  mgemm_k<2><<<dim3(4, 288), 256, 0, stream>>>(w1b, xT, nullptr, nullptr, b1,
      mu1, rs1, gamma_n, beta_n, nullptr, nullptr, nullptr,
      nullptr, nullptr, nullptr, nullptr, nullptr, hbT);
  // out = xT + W2 @ h + b2
  mgemm_k<3><<<dim3(4, 288), 256, 0, stream>>>(w2b, hbT, nullptr, xT, b2,
      nullptr, nullptr, nullptr, nullptr, nullptr, nullptr, nullptr,
      nullptr, nullptr, nullptr, nullptr, outp, nullptr);
}